// Round 1
// baseline (3907.229 us; speedup 1.0000x reference)
//
#include <hip/hip_runtime.h>
#include <math.h>

// HMM exact marginal log-lik via symmetry-collapsed Kalman filter.
// Full 66-dim filter decomposes (exactly) into:
//   - 6-dim KF over [4 class-mean bias coords (basis 1_t/sqrt(n)), 2 state coords]
//   - 4 independent scalar within-class variance recursions (closed form)
// Classes: t = 2*(k/S) + (k%2), each of size n = S/2 = 16. sqrt(n) = 4.

#define LOG2PI_D 1.8378770664093454

__launch_bounds__(256, 1)
__global__ void hmm_kf_kernel(const float* __restrict__ track,
                              const float* __restrict__ bias_scales,
                              const float* __restrict__ obs_noise,
                              const float* __restrict__ trans_noise,
                              const float* __restrict__ Amat,
                              const float* __restrict__ init_cov,
                              const int* __restrict__ num_sensors,
                              float* __restrict__ out,
                              int T, int out_size)
{
    const int tid = (int)threadIdx.x;
    __shared__ double s_partial[256];
    __shared__ double s_Q[36];
    __shared__ double s_scal[3];   // ll_main, dT(par0), dT(par1)

    const double r  = (double)obs_noise[0] * (double)obs_noise[0];
    const double q  = (double)trans_noise[0] * (double)trans_noise[0];
    const int    S  = num_sensors[0];       // 32
    const int    n  = S >> 1;               // 16 (class size)
    const double dn = (double)n;
    const double sqn = sqrt(dn);            // 4
    const double d0p0 = (double)bias_scales[0];
    const double d0p1 = (double)bias_scales[1];

    // ---- within-class logdet sum, parallel over k (threads 64..255) ----
    // c_{b,k} = d_b^{(k-1)} + r, d^{(j)} = d0*r/(r + j*d0);  sum over k=1..T of log c0 + log c1
    double partial = 0.0;
    if (tid >= 64) {
        for (int k = tid - 64; k < T; k += 192) {
            double j  = (double)k;
            double c0 = d0p0 * r / (r + j * d0p0) + r;
            double c1 = d0p1 * r / (r + j * d0p1) + r;
            partial += (double)__logf((float)c0) + (double)__logf((float)c1);
        }
    }
    s_partial[tid] = partial;

    // ---- thread 0: collapsed 6-dim Kalman scan ----
    if (tid == 0) {
        const double A00 = (double)Amat[0], A01 = (double)Amat[1];
        const double A10 = (double)Amat[2], A11 = (double)Amat[3];

        double m[6];
        double P[6][6];
        #pragma unroll
        for (int i2 = 0; i2 < 6; ++i2) {
            m[i2] = 0.0;
            #pragma unroll
            for (int j2 = 0; j2 < 6; ++j2) P[i2][j2] = 0.0;
        }
        // P_bb(class-mean) initial = diag(bias_scales[d(t)]) ; Pss = init_cov
        P[0][0] = d0p0; P[1][1] = d0p1; P[2][2] = d0p0; P[3][3] = d0p1;
        P[4][4] = (double)init_cov[0];
        {
            double off = 0.5*((double)init_cov[1] + (double)init_cov[2]);
            P[4][5] = off; P[5][4] = off;
        }
        P[5][5] = (double)init_cov[3];

        double quadsum = 0.0, logdetsum = 0.0;
        const float2* trk = (const float2*)track;
        const int gof[4] = {0,0,1,1};

        for (int k = 0; k < T; ++k) {
            // ---------------- predict ----------------
            {   // s <- A^T s
                double a4 = A00*m[4] + A10*m[5];
                double a5 = A01*m[4] + A11*m[5];
                m[4] = a4; m[5] = a5;
            }
            #pragma unroll
            for (int t = 0; t < 4; ++t) {      // C <- C A
                double c4 = P[t][4], c5 = P[t][5];
                P[t][4] = c4*A00 + c5*A10;
                P[t][5] = c4*A01 + c5*A11;
            }
            {   // Pss <- A^T Pss A + q I
                double p44=P[4][4], p45=P[4][5], p54=P[5][4], p55=P[5][5];
                double b00 = p44*A00 + p45*A10, b01 = p44*A01 + p45*A11;
                double b10 = p54*A00 + p55*A10, b11 = p54*A01 + p55*A11;
                double n44 = A00*b00 + A10*b10 + q;
                double n45 = A00*b01 + A10*b11;
                double n54 = A01*b00 + A11*b10;
                double n55 = A01*b01 + A11*b11 + q;
                double off = 0.5*(n45+n54);
                P[4][4]=n44; P[4][5]=off; P[5][4]=off; P[5][5]=n55;
            }
            #pragma unroll
            for (int t = 0; t < 4; ++t) { P[4][t] = P[t][4]; P[5][t] = P[t][5]; }

            // ---------------- update ----------------
            float2 xk = trk[k];
            double xd0 = (double)xk.x, xd1 = (double)xk.y;

            double Hp[4][6];                    // H~ P  (4x6)
            #pragma unroll
            for (int t = 0; t < 4; ++t) {
                const int gr = 4 + gof[t];
                #pragma unroll
                for (int j = 0; j < 6; ++j)
                    Hp[t][j] = P[t][j] + sqn * P[gr][j];
            }
            double Y[4][4];                     // innovation cov (4x4)
            #pragma unroll
            for (int t = 0; t < 4; ++t) {
                #pragma unroll
                for (int u = t; u < 4; ++u) {
                    double v = Hp[t][u] + sqn * Hp[t][4+gof[u]];
                    if (t == u) v += r;
                    Y[t][u] = v; Y[u][t] = v;
                }
            }
            double rv[4];                       // innovation (class-mean coords)
            rv[0] = sqn*xd0 - m[0] - sqn*m[4];
            rv[1] = sqn*xd1 - m[1] - sqn*m[4];
            rv[2] = sqn*xd0 - m[2] - sqn*m[5];
            rv[3] = sqn*xd1 - m[3] - sqn*m[5];

            // 4x4 inverse via adjugate (good ILP, no sqrt chain)
            double m00=Y[0][0], m01=Y[0][1], m02=Y[0][2], m03=Y[0][3];
            double m10=Y[1][0], m11=Y[1][1], m12=Y[1][2], m13=Y[1][3];
            double m20=Y[2][0], m21=Y[2][1], m22=Y[2][2], m23=Y[2][3];
            double m30=Y[3][0], m31=Y[3][1], m32=Y[3][2], m33=Y[3][3];
            double s0 = m00*m11 - m10*m01;
            double s1 = m00*m12 - m10*m02;
            double s2 = m00*m13 - m10*m03;
            double s3 = m01*m12 - m11*m02;
            double s4 = m01*m13 - m11*m03;
            double s5 = m02*m13 - m12*m03;
            double c5 = m22*m33 - m32*m23;
            double c4 = m21*m33 - m31*m23;
            double c3 = m21*m32 - m31*m22;
            double c2 = m20*m33 - m30*m23;
            double c1 = m20*m32 - m30*m22;
            double c0 = m20*m31 - m30*m21;
            double det = s0*c5 - s1*c4 + s2*c3 + s3*c2 - s4*c1 + s5*c0;
            double invdet = 1.0 / det;
            double Yi[4][4];
            Yi[0][0] = ( m11*c5 - m12*c4 + m13*c3) * invdet;
            Yi[0][1] = (-m01*c5 + m02*c4 - m03*c3) * invdet;
            Yi[0][2] = ( m31*s5 - m32*s4 + m33*s3) * invdet;
            Yi[0][3] = (-m21*s5 + m22*s4 - m23*s3) * invdet;
            Yi[1][0] = (-m10*c5 + m12*c2 - m13*c1) * invdet;
            Yi[1][1] = ( m00*c5 - m02*c2 + m03*c1) * invdet;
            Yi[1][2] = (-m30*s5 + m32*s2 - m33*s1) * invdet;
            Yi[1][3] = ( m20*s5 - m22*s2 + m23*s1) * invdet;
            Yi[2][0] = ( m10*c4 - m11*c2 + m13*c0) * invdet;
            Yi[2][1] = (-m00*c4 + m01*c2 - m03*c0) * invdet;
            Yi[2][2] = ( m30*s4 - m31*s2 + m33*s0) * invdet;
            Yi[2][3] = (-m20*s4 + m21*s2 - m23*s0) * invdet;
            Yi[3][0] = (-m10*c3 + m11*c1 - m12*c0) * invdet;
            Yi[3][1] = ( m00*c3 - m01*c1 + m02*c0) * invdet;
            Yi[3][2] = (-m30*s3 + m31*s1 - m32*s0) * invdet;
            Yi[3][3] = ( m20*s3 - m21*s1 + m22*s0) * invdet;

            logdetsum += (double)__logf((float)det);

            double al[4];
            #pragma unroll
            for (int t = 0; t < 4; ++t)
                al[t] = Yi[t][0]*rv[0] + Yi[t][1]*rv[1] + Yi[t][2]*rv[2] + Yi[t][3]*rv[3];
            quadsum += rv[0]*al[0] + rv[1]*al[1] + rv[2]*al[2] + rv[3]*al[3];

            // mean update: m += Hp^T alpha
            #pragma unroll
            for (int j = 0; j < 6; ++j)
                m[j] += Hp[0][j]*al[0] + Hp[1][j]*al[1] + Hp[2][j]*al[2] + Hp[3][j]*al[3];

            // P -= Hp^T (Yi Hp), symmetric
            double W[4][6];
            #pragma unroll
            for (int u = 0; u < 4; ++u) {
                #pragma unroll
                for (int j = 0; j < 6; ++j)
                    W[u][j] = Yi[u][0]*Hp[0][j] + Yi[u][1]*Hp[1][j]
                            + Yi[u][2]*Hp[2][j] + Yi[u][3]*Hp[3][j];
            }
            #pragma unroll
            for (int j = 0; j < 6; ++j) {
                #pragma unroll
                for (int l = j; l < 6; ++l) {
                    double dv = Hp[0][j]*W[0][l] + Hp[1][j]*W[1][l]
                              + Hp[2][j]*W[2][l] + Hp[3][j]*W[3][l];
                    double nv = P[j][l] - dv;
                    P[j][l] = nv; P[l][j] = nv;
                }
            }
        }

        double ll_main = -0.5*(4.0*LOG2PI_D*(double)T + quadsum) - 0.5*logdetsum;

        // ---- invert final 6x6 P (Gauss-Jordan, SPD, fully unrolled -> registers) ----
        double MI[6][12];
        #pragma unroll
        for (int i2 = 0; i2 < 6; ++i2) {
            #pragma unroll
            for (int j2 = 0; j2 < 6; ++j2) {
                MI[i2][j2]   = P[i2][j2];
                MI[i2][6+j2] = (i2 == j2) ? 1.0 : 0.0;
            }
        }
        #pragma unroll
        for (int cc = 0; cc < 6; ++cc) {
            double piv = 1.0 / MI[cc][cc];
            #pragma unroll
            for (int j2 = 0; j2 < 12; ++j2) MI[cc][j2] *= piv;
            #pragma unroll
            for (int rr = 0; rr < 6; ++rr) {
                if (rr == cc) continue;
                double f = MI[rr][cc];
                #pragma unroll
                for (int j2 = 0; j2 < 12; ++j2) MI[rr][j2] -= f * MI[cc][j2];
            }
        }
        #pragma unroll
        for (int i2 = 0; i2 < 6; ++i2) {
            #pragma unroll
            for (int j2 = 0; j2 < 6; ++j2)
                s_Q[i2*6+j2] = 0.5*(MI[i2][6+j2] + MI[j2][6+i2]);
        }
        s_scal[0] = ll_main;
        s_scal[1] = d0p0 * r / (r + (double)T * d0p0);   // d_T, parity 0
        s_scal[2] = d0p1 * r / (r + (double)T * d0p1);   // d_T, parity 1
    }

    __syncthreads();
    // reduce within-class partial sums
    for (int s2 = 128; s2 > 0; s2 >>= 1) {
        if (tid < s2) s_partial[tid] += s_partial[tid + s2];
        __syncthreads();
    }

    const double Lsum = s_partial[0];
    // ll_within = -2(n-1) log2pi * T - (n-1) * Lsum   (60 within-dims/step)
    const double logp = s_scal[0] - 2.0*(dn - 1.0)*LOG2PI_D*(double)T - (dn - 1.0)*Lsum;
    const double dTp0 = s_scal[1], dTp1 = s_scal[2];
    const double inv_sqn = 1.0 / sqn;
    const int D  = 2*S + 2;   // 66
    const int ob = D - 2;     // 64

    // precision = lift(inv(P~)) + sum_t (1/dT_t) * within-class projector
    for (int idx = tid; idx < out_size; idx += 256) {
        double v;
        if (idx == 0) {
            v = logp;
        } else {
            int e = idx - 1;
            int row = e / D;
            int col = e - row * D;
            if (row < ob && col < ob) {
                int tr = ((row / S) << 1) | (row & 1);
                int tc = ((col / S) << 1) | (col & 1);
                v = s_Q[tr*6 + tc] / dn;
                if (tr == tc) {
                    double dt = (tr & 1) ? dTp1 : dTp0;
                    v -= 1.0 / (dn * dt);
                    if (row == col) v += 1.0 / dt;
                }
            } else if (row < ob) {
                int tr = ((row / S) << 1) | (row & 1);
                v = s_Q[tr*6 + 4 + (col - ob)] * inv_sqn;
            } else if (col < ob) {
                int tc = ((col / S) << 1) | (col & 1);
                v = s_Q[(4 + row - ob)*6 + tc] * inv_sqn;
            } else {
                v = s_Q[(4 + row - ob)*6 + (4 + col - ob)];
            }
        }
        out[idx] = (float)v;
    }
}

extern "C" void kernel_launch(void* const* d_in, const int* in_sizes, int n_in,
                              void* d_out, int out_size, void* d_ws, size_t ws_size,
                              hipStream_t stream) {
    const float* track        = (const float*)d_in[0];
    const float* bias_scales  = (const float*)d_in[1];
    const float* obs_noise    = (const float*)d_in[2];
    const float* trans_noise  = (const float*)d_in[3];
    const float* Amat         = (const float*)d_in[4];
    const float* init_cov     = (const float*)d_in[5];
    const int*   num_sensors  = (const int*)d_in[6];
    int T = in_sizes[0] / 2;   // track is (T, 2)

    hmm_kf_kernel<<<1, 256, 0, stream>>>(track, bias_scales, obs_noise, trans_noise,
                                         Amat, init_cov, num_sensors,
                                         (float*)d_out, T, out_size);
}

// Round 2
// 396.351 us; speedup vs baseline: 9.8580x; 9.8580x over previous
//
#include <hip/hip_runtime.h>
#include <math.h>

// Parallel-scan Kalman filter (Sarkka & Garcia-Fernandez association) over the
// symmetry-collapsed 6-dim model. f32 elements (threshold is 6635 absolute).
//
// Element layout (120 floats, stride 128): A[36], C[36], J[36], b[6], e[6]
//   p(x_out|x_in) = N(A x_in + b, C);  p(data|x_in) ~ exp(-1/2 x'Jx + e'x)

#define LOG2PI_D 1.8378770664093454
#define CHUNK 8
#define ESTRIDE 128
#define DEVFN __device__ __forceinline__

DEVFN void mul66(const float* A, const float* B, float* D) {        // D = A*B
    #pragma unroll
    for (int i = 0; i < 6; ++i)
        #pragma unroll
        for (int j = 0; j < 6; ++j) {
            float s = 0.f;
            #pragma unroll
            for (int k = 0; k < 6; ++k) s += A[i*6+k] * B[k*6+j];
            D[i*6+j] = s;
        }
}
DEVFN void mulT66(const float* A, const float* B, float* D) {       // D = A*B^T
    #pragma unroll
    for (int i = 0; i < 6; ++i)
        #pragma unroll
        for (int j = 0; j < 6; ++j) {
            float s = 0.f;
            #pragma unroll
            for (int k = 0; k < 6; ++k) s += A[i*6+k] * B[j*6+k];
            D[i*6+j] = s;
        }
}
DEVFN void tmul66(const float* A, const float* B, float* D) {       // D = A^T*B
    #pragma unroll
    for (int i = 0; i < 6; ++i)
        #pragma unroll
        for (int j = 0; j < 6; ++j) {
            float s = 0.f;
            #pragma unroll
            for (int k = 0; k < 6; ++k) s += A[k*6+i] * B[k*6+j];
            D[i*6+j] = s;
        }
}
DEVFN void mv6(const float* A, const float* x, float* y) {          // y = A x
    #pragma unroll
    for (int i = 0; i < 6; ++i) {
        float s = 0.f;
        #pragma unroll
        for (int j = 0; j < 6; ++j) s += A[i*6+j] * x[j];
        y[i] = s;
    }
}
DEVFN void tmv6(const float* A, const float* x, float* y) {         // y = A^T x
    #pragma unroll
    for (int i = 0; i < 6; ++i) {
        float s = 0.f;
        #pragma unroll
        for (int j = 0; j < 6; ++j) s += A[j*6+i] * x[j];
        y[i] = s;
    }
}
DEVFN void mv64(const float* K, const float* y, float* o) {         // (6x4) * (4)
    #pragma unroll
    for (int i = 0; i < 6; ++i) {
        float s = 0.f;
        #pragma unroll
        for (int t = 0; t < 4; ++t) s += K[i*4+t] * y[t];
        o[i] = s;
    }
}

DEVFN void inv6(const float* A, float* Ai) {    // Gauss-Jordan, diag >= 1 (I + PSD*PSD)
    float M[6][12];
    #pragma unroll
    for (int i = 0; i < 6; ++i)
        #pragma unroll
        for (int j = 0; j < 6; ++j) {
            M[i][j]   = A[i*6+j];
            M[i][6+j] = (i == j) ? 1.f : 0.f;
        }
    #pragma unroll
    for (int c = 0; c < 6; ++c) {
        float piv = 1.f / M[c][c];
        #pragma unroll
        for (int j = 0; j < 12; ++j) M[c][j] *= piv;
        #pragma unroll
        for (int rr = 0; rr < 6; ++rr) {
            if (rr == c) continue;
            float f = M[rr][c];
            #pragma unroll
            for (int j = 0; j < 12; ++j) M[rr][j] -= f * M[c][j];
        }
    }
    #pragma unroll
    for (int i = 0; i < 6; ++i)
        #pragma unroll
        for (int j = 0; j < 6; ++j) Ai[i*6+j] = M[i][6+j];
}

DEVFN float inv4(const float* Y, float* Yi) {   // adjugate; returns det
    float m00=Y[0], m01=Y[1], m02=Y[2], m03=Y[3];
    float m10=Y[4], m11=Y[5], m12=Y[6], m13=Y[7];
    float m20=Y[8], m21=Y[9], m22=Y[10], m23=Y[11];
    float m30=Y[12], m31=Y[13], m32=Y[14], m33=Y[15];
    float s0 = m00*m11 - m10*m01;
    float s1 = m00*m12 - m10*m02;
    float s2 = m00*m13 - m10*m03;
    float s3 = m01*m12 - m11*m02;
    float s4 = m01*m13 - m11*m03;
    float s5 = m02*m13 - m12*m03;
    float c5 = m22*m33 - m32*m23;
    float c4 = m21*m33 - m31*m23;
    float c3 = m21*m32 - m31*m22;
    float c2 = m20*m33 - m30*m23;
    float c1 = m20*m32 - m30*m22;
    float c0 = m20*m31 - m30*m21;
    float det = s0*c5 - s1*c4 + s2*c3 + s3*c2 - s4*c1 + s5*c0;
    float inv = 1.0f / det;
    Yi[0]  = ( m11*c5 - m12*c4 + m13*c3) * inv;
    Yi[1]  = (-m01*c5 + m02*c4 - m03*c3) * inv;
    Yi[2]  = ( m31*s5 - m32*s4 + m33*s3) * inv;
    Yi[3]  = (-m21*s5 + m22*s4 - m23*s3) * inv;
    Yi[4]  = (-m10*c5 + m12*c2 - m13*c1) * inv;
    Yi[5]  = ( m00*c5 - m02*c2 + m03*c1) * inv;
    Yi[6]  = (-m30*s5 + m32*s2 - m33*s1) * inv;
    Yi[7]  = ( m20*s5 - m22*s2 + m23*s1) * inv;
    Yi[8]  = ( m10*c4 - m11*c2 + m13*c0) * inv;
    Yi[9]  = (-m00*c4 + m01*c2 - m03*c0) * inv;
    Yi[10] = ( m30*s4 - m31*s2 + m33*s0) * inv;
    Yi[11] = (-m20*s4 + m21*s2 - m23*s0) * inv;
    Yi[12] = (-m10*c3 + m11*c1 - m12*c0) * inv;
    Yi[13] = ( m00*c3 - m01*c1 + m02*c0) * inv;
    Yi[14] = (-m30*s3 + m31*s1 - m32*s0) * inv;
    Yi[15] = ( m20*s3 - m21*s1 + m22*s0) * inv;
    return det;
}

// combine(u=earlier(1), v=later(2)) -> O.  O must not alias inputs.
DEVFN void combine6(const float* A1, const float* C1, const float* J1,
                    const float* b1, const float* e1,
                    const float* A2, const float* C2, const float* J2,
                    const float* b2, const float* e2,
                    float* OA, float* OC, float* OJ, float* Ob, float* Oe)
{
    float T1[36], M[36], T2[36], T3[36];
    mul66(C1, J2, T1);
    #pragma unroll
    for (int i = 0; i < 6; ++i) T1[i*6+i] += 1.f;
    inv6(T1, M);                     // M = (I + C1 J2)^-1
    mul66(A2, M, T2);                // T2 = A2 M
    mul66(T2, A1, OA);               // A  = A2 M A1
    mul66(T2, C1, T3);               // T3 = A2 M C1
    mulT66(T3, A2, OC);              // C  = T3 A2^T + C2 (symmetrized)
    #pragma unroll
    for (int i = 0; i < 6; ++i)
        #pragma unroll
        for (int j = 0; j <= i; ++j) {
            float v = 0.5f * (OC[i*6+j] + OC[j*6+i]) + 0.5f * (C2[i*6+j] + C2[j*6+i]);
            OC[i*6+j] = v; OC[j*6+i] = v;
        }
    float v6[6], u6[6], w6[6];
    mv6(C1, e2, v6);                 // b = A2 M (b1 + C1 e2) + b2
    #pragma unroll
    for (int i = 0; i < 6; ++i) v6[i] += b1[i];
    mv6(T2, v6, u6);
    #pragma unroll
    for (int i = 0; i < 6; ++i) Ob[i] = u6[i] + b2[i];
    mv6(J2, b1, w6);                 // e = A1^T M^T (e2 - J2 b1) + e1
    #pragma unroll
    for (int i = 0; i < 6; ++i) w6[i] = e2[i] - w6[i];
    tmv6(M, w6, v6);
    tmv6(A1, v6, u6);
    #pragma unroll
    for (int i = 0; i < 6; ++i) Oe[i] = u6[i] + e1[i];
    tmul66(M, J2, T1);               // J = A1^T M^T J2 A1 + J1 (symmetrized)
    tmul66(A1, T1, T3);
    mul66(T3, A1, OJ);
    #pragma unroll
    for (int i = 0; i < 6; ++i)
        #pragma unroll
        for (int j = 0; j <= i; ++j) {
            float v = 0.5f * (OJ[i*6+j] + OJ[j*6+i]) + 0.5f * (J1[i*6+j] + J1[j*6+i]);
            OJ[i*6+j] = v; OJ[j*6+i] = v;
        }
}

DEVFN void build_FHQ(float* F, float* H, float* Qm,
                     float A00, float A01, float A10, float A11, float sq, float q) {
    #pragma unroll
    for (int i = 0; i < 36; ++i) { F[i] = 0.f; Qm[i] = 0.f; }
    #pragma unroll
    for (int i = 0; i < 24; ++i) H[i] = 0.f;
    F[0*6+0] = 1.f; F[1*6+1] = 1.f; F[2*6+2] = 1.f; F[3*6+3] = 1.f;
    F[4*6+4] = A00; F[4*6+5] = A10; F[5*6+4] = A01; F[5*6+5] = A11;   // F_ss = A^T
    H[0*6+0] = 1.f; H[1*6+1] = 1.f; H[2*6+2] = 1.f; H[3*6+3] = 1.f;
    H[0*6+4] = sq;  H[1*6+4] = sq;  H[2*6+5] = sq;  H[3*6+5] = sq;
    Qm[4*6+4] = q;  Qm[5*6+5] = q;
}

DEVFN void build_P0(float* P, const float* bias_scales, const float* init_cov) {
    #pragma unroll
    for (int i = 0; i < 36; ++i) P[i] = 0.f;
    float b0 = bias_scales[0], b1 = bias_scales[1];
    P[0*6+0] = b0; P[1*6+1] = b1; P[2*6+2] = b0; P[3*6+3] = b1;
    P[4*6+4] = init_cov[0];
    float off = 0.5f * (init_cov[1] + init_cov[2]);
    P[4*6+5] = off; P[5*6+4] = off;
    P[5*6+5] = init_cov[3];
}

// ---------------- Phase A: build chunk elements ----------------
__launch_bounds__(256, 1)
__global__ void k_chunks(const float* __restrict__ track, const float* __restrict__ bias_scales,
                         const float* __restrict__ obs_noise, const float* __restrict__ trans_noise,
                         const float* __restrict__ Amat, const float* __restrict__ init_cov,
                         const int* __restrict__ num_sensors,
                         float* __restrict__ E0, int T, int NCH)
{
    __shared__ float sA[36], sC[36], sJ[36], sK[24], sN[24];
    const int tid = (int)threadIdx.x;
    const int c = (int)blockIdx.x * 256 + tid;

    const float r  = obs_noise[0] * obs_noise[0];
    const float q  = trans_noise[0] * trans_noise[0];
    const int   S  = num_sensors[0];
    const float sq = sqrtf((float)(S >> 1));
    const float A00 = Amat[0], A01 = Amat[1], A10 = Amat[2], A11 = Amat[3];

    if (tid == 0) {   // time-invariant leaf constants (shared per block)
        float F[36], H[24], Qm[36];
        build_FHQ(F, H, Qm, A00, A01, A10, A11, sq, q);
        float HQ[24];
        for (int t = 0; t < 4; ++t)
            for (int j = 0; j < 6; ++j) {
                float s = 0.f;
                for (int k = 0; k < 6; ++k) s += H[t*6+k] * Qm[k*6+j];
                HQ[t*6+j] = s;
            }
        float Sm[16];
        for (int t = 0; t < 4; ++t)
            for (int u = 0; u < 4; ++u) {
                float s = 0.f;
                for (int j = 0; j < 6; ++j) s += HQ[t*6+j] * H[u*6+j];
                Sm[t*4+u] = s + ((t == u) ? r : 0.f);
            }
        float Si[16]; inv4(Sm, Si);
        float QHt[24];
        for (int i = 0; i < 6; ++i)
            for (int t = 0; t < 4; ++t) {
                float s = 0.f;
                for (int j = 0; j < 6; ++j) s += Qm[i*6+j] * H[t*6+j];
                QHt[i*4+t] = s;
            }
        float Kst[24];
        for (int i = 0; i < 6; ++i)
            for (int t = 0; t < 4; ++t) {
                float s = 0.f;
                for (int u = 0; u < 4; ++u) s += QHt[i*4+u] * Si[u*4+t];
                Kst[i*4+t] = s;
            }
        float HF[24];
        for (int t = 0; t < 4; ++t)
            for (int j = 0; j < 6; ++j) {
                float s = 0.f;
                for (int k = 0; k < 6; ++k) s += H[t*6+k] * F[k*6+j];
                HF[t*6+j] = s;
            }
        float Ct[36], Jt[36], Nst[24];
        for (int i = 0; i < 6; ++i)
            for (int j = 0; j < 6; ++j) {
                float s = 0.f;
                for (int t = 0; t < 4; ++t) s += Kst[i*4+t] * HF[t*6+j];
                sA[i*6+j] = F[i*6+j] - s;
                float s2 = 0.f;
                for (int t = 0; t < 4; ++t) s2 += Kst[i*4+t] * HQ[t*6+j];
                Ct[i*6+j] = Qm[i*6+j] - s2;
            }
        for (int i = 0; i < 6; ++i)
            for (int t = 0; t < 4; ++t) {
                float s = 0.f;
                for (int u = 0; u < 4; ++u) s += HF[u*6+i] * Si[u*4+t];
                Nst[i*4+t] = s;
            }
        for (int i = 0; i < 6; ++i)
            for (int j = 0; j < 6; ++j) {
                float s = 0.f;
                for (int t = 0; t < 4; ++t) s += Nst[i*4+t] * HF[t*6+j];
                Jt[i*6+j] = s;
            }
        for (int i = 0; i < 6; ++i)
            for (int j = 0; j < 6; ++j) {
                sC[i*6+j] = 0.5f * (Ct[i*6+j] + Ct[j*6+i]);
                sJ[i*6+j] = 0.5f * (Jt[i*6+j] + Jt[j*6+i]);
            }
        for (int i = 0; i < 24; ++i) { sK[i] = Kst[i]; sN[i] = Nst[i]; }
    }
    __syncthreads();
    if (c >= NCH) return;

    float aA[36], aC[36], aJ[36], ab[6], ae[6];
    const int t0  = c * CHUNK;
    const int nst = min(CHUNK, T - t0);

    if (c == 0) {  // prior-rooted element for step 1
        float F[36], H[24], Qm[36];
        build_FHQ(F, H, Qm, A00, A01, A10, A11, sq, q);
        float P0[36]; build_P0(P0, bias_scales, init_cov);
        float T1[36], Pm[36];
        mul66(F, P0, T1); mulT66(T1, F, Pm);
        for (int i = 0; i < 6; ++i)
            for (int j = 0; j <= i; ++j) {
                float v = 0.5f * (Pm[i*6+j] + Pm[j*6+i]) + 0.5f * (Qm[i*6+j] + Qm[j*6+i]);
                Pm[i*6+j] = v; Pm[j*6+i] = v;
            }
        float HP[24];
        for (int t = 0; t < 4; ++t)
            for (int j = 0; j < 6; ++j) {
                float s = 0.f;
                for (int k = 0; k < 6; ++k) s += H[t*6+k] * Pm[k*6+j];
                HP[t*6+j] = s;
            }
        float S1[16];
        for (int t = 0; t < 4; ++t)
            for (int u = 0; u < 4; ++u) {
                float s = 0.f;
                for (int j = 0; j < 6; ++j) s += HP[t*6+j] * H[u*6+j];
                S1[t*4+u] = s + ((t == u) ? r : 0.f);
            }
        float Si1[16]; inv4(S1, Si1);
        float Kg[24];
        for (int i = 0; i < 6; ++i)
            for (int t = 0; t < 4; ++t) {
                float s = 0.f;
                for (int u = 0; u < 4; ++u) s += HP[u*6+i] * Si1[u*4+t];
                Kg[i*4+t] = s;
            }
        float x0 = track[0], x1 = track[1];
        float y1[4] = { sq*x0, sq*x1, sq*x0, sq*x1 };
        mv64(Kg, y1, ab);
        for (int i = 0; i < 6; ++i)
            for (int j = 0; j < 6; ++j) {
                float s = 0.f;
                for (int t = 0; t < 4; ++t) s += Kg[i*4+t] * HP[t*6+j];
                aC[i*6+j] = Pm[i*6+j] - s;
            }
        for (int i = 0; i < 6; ++i)
            for (int j = 0; j < i; ++j) {
                float v = 0.5f * (aC[i*6+j] + aC[j*6+i]);
                aC[i*6+j] = v; aC[j*6+i] = v;
            }
        #pragma unroll
        for (int i = 0; i < 36; ++i) { aA[i] = 0.f; aJ[i] = 0.f; }
        #pragma unroll
        for (int i = 0; i < 6; ++i) ae[i] = 0.f;
    } else {       // TI leaf for step t0+1
        #pragma unroll
        for (int i = 0; i < 36; ++i) { aA[i] = sA[i]; aC[i] = sC[i]; aJ[i] = sJ[i]; }
        float x0 = track[2*t0], x1 = track[2*t0+1];
        float y[4] = { sq*x0, sq*x1, sq*x0, sq*x1 };
        mv64(sK, y, ab);
        mv64(sN, y, ae);
    }

    for (int s = 1; s < nst; ++s) {
        int row = t0 + s;
        float x0 = track[2*row], x1 = track[2*row+1];
        float y[4] = { sq*x0, sq*x1, sq*x0, sq*x1 };
        float lb[6], le[6];
        mv64(sK, y, lb);
        mv64(sN, y, le);
        float oA[36], oC[36], oJ[36], ob[6], oe[6];
        combine6(aA, aC, aJ, ab, ae, sA, sC, sJ, lb, le, oA, oC, oJ, ob, oe);
        #pragma unroll
        for (int i = 0; i < 36; ++i) { aA[i] = oA[i]; aC[i] = oC[i]; aJ[i] = oJ[i]; }
        #pragma unroll
        for (int i = 0; i < 6; ++i) { ab[i] = ob[i]; ae[i] = oe[i]; }
    }

    float* dst = E0 + (size_t)c * ESTRIDE;
    #pragma unroll
    for (int i = 0; i < 36; ++i) { dst[i] = aA[i]; dst[36+i] = aC[i]; dst[72+i] = aJ[i]; }
    #pragma unroll
    for (int i = 0; i < 6; ++i) { dst[108+i] = ab[i]; dst[114+i] = ae[i]; }
}

// ---------------- Phase B: one Hillis-Steele scan level ----------------
__launch_bounds__(256, 1)
__global__ void k_scan(const float* __restrict__ src, float* __restrict__ dst, int off, int NCH)
{
    const int i = (int)blockIdx.x * 256 + (int)threadIdx.x;
    if (i >= NCH) return;
    const float* ps = src + (size_t)i * ESTRIDE;
    float* pd = dst + (size_t)i * ESTRIDE;
    if (i < off) {
        #pragma unroll 8
        for (int k = 0; k < 120; ++k) pd[k] = ps[k];
        return;
    }
    const float* pl = src + (size_t)(i - off) * ESTRIDE;
    float A1[36], C1[36], J1[36], b1[6], e1[6];
    float A2[36], C2[36], J2[36], b2[6], e2[6];
    #pragma unroll
    for (int k = 0; k < 36; ++k) { A1[k] = pl[k]; C1[k] = pl[36+k]; J1[k] = pl[72+k]; }
    #pragma unroll
    for (int k = 0; k < 6; ++k)  { b1[k] = pl[108+k]; e1[k] = pl[114+k]; }
    #pragma unroll
    for (int k = 0; k < 36; ++k) { A2[k] = ps[k]; C2[k] = ps[36+k]; J2[k] = ps[72+k]; }
    #pragma unroll
    for (int k = 0; k < 6; ++k)  { b2[k] = ps[108+k]; e2[k] = ps[114+k]; }
    float OA[36], OC[36], OJ[36], Ob[6], Oe[6];
    combine6(A1, C1, J1, b1, e1, A2, C2, J2, b2, e2, OA, OC, OJ, Ob, Oe);
    #pragma unroll
    for (int k = 0; k < 36; ++k) { pd[k] = OA[k]; pd[36+k] = OC[k]; pd[72+k] = OJ[k]; }
    #pragma unroll
    for (int k = 0; k < 6; ++k)  { pd[108+k] = Ob[k]; pd[114+k] = Oe[k]; }
}

// ---------------- Phase C: per-chunk standard KF, log-lik terms ----------------
__launch_bounds__(256, 1)
__global__ void k_ll(const float* __restrict__ track, const float* __restrict__ bias_scales,
                     const float* __restrict__ obs_noise, const float* __restrict__ trans_noise,
                     const float* __restrict__ Amat, const float* __restrict__ init_cov,
                     const int* __restrict__ num_sensors, const float* __restrict__ Efin,
                     double* __restrict__ partials, float* __restrict__ PT, int T, int NCH)
{
    const int c = (int)blockIdx.x * 256 + (int)threadIdx.x;
    if (c >= NCH) return;

    const float r  = obs_noise[0] * obs_noise[0];
    const float q  = trans_noise[0] * trans_noise[0];
    const int   S  = num_sensors[0];
    const float sq = sqrtf((float)(S >> 1));
    const float A00 = Amat[0], A01 = Amat[1], A10 = Amat[2], A11 = Amat[3];
    const int gof[4] = {0, 0, 1, 1};

    float m[6], P[6][6];
    if (c == 0) {
        float P0[36]; build_P0(P0, bias_scales, init_cov);
        #pragma unroll
        for (int i = 0; i < 6; ++i) {
            m[i] = 0.f;
            #pragma unroll
            for (int j = 0; j < 6; ++j) P[i][j] = P0[i*6+j];
        }
    } else {
        const float* e = Efin + (size_t)(c - 1) * ESTRIDE;
        #pragma unroll
        for (int i = 0; i < 6; ++i) {
            m[i] = e[108+i];
            #pragma unroll
            for (int j = 0; j < 6; ++j) P[i][j] = e[36 + i*6 + j];
        }
    }

    float quad = 0.f, logdet = 0.f;
    const int t0 = c * CHUNK;
    const int nst = min(CHUNK, T - t0);

    for (int s = 0; s < nst; ++s) {
        // predict
        {
            float a4 = A00*m[4] + A10*m[5];
            float a5 = A01*m[4] + A11*m[5];
            m[4] = a4; m[5] = a5;
        }
        #pragma unroll
        for (int t = 0; t < 4; ++t) {
            float c4 = P[t][4], c5 = P[t][5];
            P[t][4] = c4*A00 + c5*A10;
            P[t][5] = c4*A01 + c5*A11;
        }
        {
            float p44 = P[4][4], p45 = P[4][5], p54 = P[5][4], p55 = P[5][5];
            float b00 = p44*A00 + p45*A10, b01 = p44*A01 + p45*A11;
            float b10 = p54*A00 + p55*A10, b11 = p54*A01 + p55*A11;
            float n44 = A00*b00 + A10*b10 + q;
            float n45 = A00*b01 + A10*b11;
            float n54 = A01*b00 + A11*b10;
            float n55 = A01*b01 + A11*b11 + q;
            float off = 0.5f * (n45 + n54);
            P[4][4] = n44; P[4][5] = off; P[5][4] = off; P[5][5] = n55;
        }
        #pragma unroll
        for (int t = 0; t < 4; ++t) { P[4][t] = P[t][4]; P[5][t] = P[t][5]; }

        // update
        int row = t0 + s;
        float x0 = track[2*row], x1 = track[2*row+1];
        float Hp[4][6];
        #pragma unroll
        for (int t = 0; t < 4; ++t) {
            const int gr = 4 + gof[t];
            #pragma unroll
            for (int j = 0; j < 6; ++j) Hp[t][j] = P[t][j] + sq * P[gr][j];
        }
        float Y[16];
        #pragma unroll
        for (int t = 0; t < 4; ++t)
            #pragma unroll
            for (int u = 0; u < 4; ++u) {
                float v = Hp[t][u] + sq * Hp[t][4+gof[u]];
                if (t == u) v += r;
                Y[t*4+u] = v;
            }
        float rv[4];
        rv[0] = sq*x0 - m[0] - sq*m[4];
        rv[1] = sq*x1 - m[1] - sq*m[4];
        rv[2] = sq*x0 - m[2] - sq*m[5];
        rv[3] = sq*x1 - m[3] - sq*m[5];

        float Yi[16];
        float det = inv4(Y, Yi);
        logdet += __logf(det);

        float al[4];
        #pragma unroll
        for (int t = 0; t < 4; ++t)
            al[t] = Yi[t*4+0]*rv[0] + Yi[t*4+1]*rv[1] + Yi[t*4+2]*rv[2] + Yi[t*4+3]*rv[3];
        quad += rv[0]*al[0] + rv[1]*al[1] + rv[2]*al[2] + rv[3]*al[3];

        #pragma unroll
        for (int j = 0; j < 6; ++j)
            m[j] += Hp[0][j]*al[0] + Hp[1][j]*al[1] + Hp[2][j]*al[2] + Hp[3][j]*al[3];

        float W[4][6];
        #pragma unroll
        for (int u = 0; u < 4; ++u)
            #pragma unroll
            for (int j = 0; j < 6; ++j)
                W[u][j] = Yi[u*4+0]*Hp[0][j] + Yi[u*4+1]*Hp[1][j]
                        + Yi[u*4+2]*Hp[2][j] + Yi[u*4+3]*Hp[3][j];
        #pragma unroll
        for (int j = 0; j < 6; ++j)
            #pragma unroll
            for (int l = j; l < 6; ++l) {
                float dv = Hp[0][j]*W[0][l] + Hp[1][j]*W[1][l]
                         + Hp[2][j]*W[2][l] + Hp[3][j]*W[3][l];
                float nv = P[j][l] - dv;
                P[j][l] = nv; P[l][j] = nv;
            }
    }

    partials[c] = -0.5 * (4.0 * LOG2PI_D * (double)nst + (double)quad) - 0.5 * (double)logdet;
    if (c == NCH - 1) {
        #pragma unroll
        for (int i = 0; i < 6; ++i)
            #pragma unroll
            for (int j = 0; j < 6; ++j) PT[i*6+j] = P[i][j];
    }
}

// ---------------- Phase D: reduce + within-class + invert + scatter ----------------
__launch_bounds__(256, 1)
__global__ void k_final(const float* __restrict__ bias_scales, const float* __restrict__ obs_noise,
                        const float* __restrict__ trans_noise, const int* __restrict__ num_sensors,
                        const double* __restrict__ partials, const float* __restrict__ PT,
                        float* __restrict__ out, int out_size, int T, int NCH)
{
    const int tid = (int)threadIdx.x;
    __shared__ double s_partial[256];
    __shared__ double s_red[256];
    __shared__ double s_Q[36];
    __shared__ double s_scal[3];

    const double r  = (double)obs_noise[0] * (double)obs_noise[0];
    const int    S  = num_sensors[0];
    const int    n  = S >> 1;
    const double dn = (double)n;
    const double sqn = sqrt(dn);
    const double d0p0 = (double)bias_scales[0];
    const double d0p1 = (double)bias_scales[1];

    // within-class logdet sum (closed form), threads 64..255
    double partial = 0.0;
    if (tid >= 64) {
        for (int k = tid - 64; k < T; k += 192) {
            double j  = (double)k;
            double c0 = d0p0 * r / (r + j * d0p0) + r;
            double c1 = d0p1 * r / (r + j * d0p1) + r;
            partial += (double)__logf((float)c0) + (double)__logf((float)c1);
        }
    }
    s_partial[tid] = partial;

    double ps = 0.0;
    for (int i = tid; i < NCH; i += 256) ps += partials[i];
    s_red[tid] = ps;

    if (tid == 0) {
        double MI[6][12];
        #pragma unroll
        for (int i = 0; i < 6; ++i)
            #pragma unroll
            for (int j = 0; j < 6; ++j) {
                MI[i][j]   = 0.5 * ((double)PT[i*6+j] + (double)PT[j*6+i]);
                MI[i][6+j] = (i == j) ? 1.0 : 0.0;
            }
        #pragma unroll
        for (int cc = 0; cc < 6; ++cc) {
            double piv = 1.0 / MI[cc][cc];
            #pragma unroll
            for (int j = 0; j < 12; ++j) MI[cc][j] *= piv;
            #pragma unroll
            for (int rr = 0; rr < 6; ++rr) {
                if (rr == cc) continue;
                double f = MI[rr][cc];
                #pragma unroll
                for (int j = 0; j < 12; ++j) MI[rr][j] -= f * MI[cc][j];
            }
        }
        #pragma unroll
        for (int i = 0; i < 6; ++i)
            #pragma unroll
            for (int j = 0; j < 6; ++j)
                s_Q[i*6+j] = 0.5 * (MI[i][6+j] + MI[j][6+i]);
        s_scal[1] = d0p0 * r / (r + (double)T * d0p0);
        s_scal[2] = d0p1 * r / (r + (double)T * d0p1);
    }
    __syncthreads();

    for (int s2 = 128; s2 > 0; s2 >>= 1) {
        if (tid < s2) {
            s_partial[tid] += s_partial[tid + s2];
            s_red[tid]     += s_red[tid + s2];
        }
        __syncthreads();
    }

    const double Lsum    = s_partial[0];
    const double ll_main = s_red[0];
    const double logp = ll_main - 2.0*(dn - 1.0)*LOG2PI_D*(double)T - (dn - 1.0)*Lsum;
    const double dTp0 = s_scal[1], dTp1 = s_scal[2];
    const double inv_sqn = 1.0 / sqn;
    const int D  = 2*S + 2;
    const int ob = D - 2;

    for (int idx = tid; idx < out_size; idx += 256) {
        double v;
        if (idx == 0) {
            v = logp;
        } else {
            int e = idx - 1;
            int row = e / D;
            int col = e - row * D;
            if (row < ob && col < ob) {
                int tr = ((row / S) << 1) | (row & 1);
                int tc = ((col / S) << 1) | (col & 1);
                v = s_Q[tr*6 + tc] / dn;
                if (tr == tc) {
                    double dt = (tr & 1) ? dTp1 : dTp0;
                    v -= 1.0 / (dn * dt);
                    if (row == col) v += 1.0 / dt;
                }
            } else if (row < ob) {
                int tr = ((row / S) << 1) | (row & 1);
                v = s_Q[tr*6 + 4 + (col - ob)] * inv_sqn;
            } else if (col < ob) {
                int tc = ((col / S) << 1) | (col & 1);
                v = s_Q[(4 + row - ob)*6 + tc] * inv_sqn;
            } else {
                v = s_Q[(4 + row - ob)*6 + (4 + col - ob)];
            }
        }
        out[idx] = (float)v;
    }
}

extern "C" void kernel_launch(void* const* d_in, const int* in_sizes, int n_in,
                              void* d_out, int out_size, void* d_ws, size_t ws_size,
                              hipStream_t stream) {
    const float* track        = (const float*)d_in[0];
    const float* bias_scales  = (const float*)d_in[1];
    const float* obs_noise    = (const float*)d_in[2];
    const float* trans_noise  = (const float*)d_in[3];
    const float* Amat         = (const float*)d_in[4];
    const float* init_cov     = (const float*)d_in[5];
    const int*   num_sensors  = (const int*)d_in[6];

    const int T   = in_sizes[0] / 2;
    const int NCH = (T + CHUNK - 1) / CHUNK;          // 512 for T=4096

    float* E0 = (float*)d_ws;
    float* E1 = E0 + (size_t)NCH * ESTRIDE;
    float* PT = E1 + (size_t)NCH * ESTRIDE;
    double* partials = (double*)(PT + 38);            // 8B-aligned (even float offset)

    const int nb = (NCH + 255) / 256;

    k_chunks<<<nb, 256, 0, stream>>>(track, bias_scales, obs_noise, trans_noise,
                                     Amat, init_cov, num_sensors, E0, T, NCH);

    float* src = E0; float* dst = E1;
    for (int off = 1; off < NCH; off <<= 1) {
        k_scan<<<nb, 256, 0, stream>>>(src, dst, off, NCH);
        float* tmp = src; src = dst; dst = tmp;
    }

    k_ll<<<nb, 256, 0, stream>>>(track, bias_scales, obs_noise, trans_noise,
                                 Amat, init_cov, num_sensors, src, partials, PT, T, NCH);

    k_final<<<1, 256, 0, stream>>>(bias_scales, obs_noise, trans_noise, num_sensors,
                                   partials, PT, (float*)d_out, out_size, T, NCH);
}

// Round 3
// 269.016 us; speedup vs baseline: 14.5241x; 1.4733x over previous
//
#include <hip/hip_runtime.h>
#include <math.h>

// Parallel Kalman filter over the symmetry-collapsed 6-dim model, exploiting
// time-invariance: chunk covariances are data-independent (doubling-table
// powers of the chunk element), data enters only through a 6-dim affine scan.

#define LOG2PI_D 1.8378770664093454
#define CHUNK 16
#define DEVFN __device__ __forceinline__

// ---------- dense helpers (proven in round 1) ----------
DEVFN void mul66(const float* A, const float* B, float* D) {        // D = A*B
    #pragma unroll
    for (int i = 0; i < 6; ++i)
        #pragma unroll
        for (int j = 0; j < 6; ++j) {
            float s = 0.f;
            #pragma unroll
            for (int k = 0; k < 6; ++k) s += A[i*6+k] * B[k*6+j];
            D[i*6+j] = s;
        }
}
DEVFN void mulT66(const float* A, const float* B, float* D) {       // D = A*B^T
    #pragma unroll
    for (int i = 0; i < 6; ++i)
        #pragma unroll
        for (int j = 0; j < 6; ++j) {
            float s = 0.f;
            #pragma unroll
            for (int k = 0; k < 6; ++k) s += A[i*6+k] * B[j*6+k];
            D[i*6+j] = s;
        }
}
DEVFN void tmul66(const float* A, const float* B, float* D) {       // D = A^T*B
    #pragma unroll
    for (int i = 0; i < 6; ++i)
        #pragma unroll
        for (int j = 0; j < 6; ++j) {
            float s = 0.f;
            #pragma unroll
            for (int k = 0; k < 6; ++k) s += A[k*6+i] * B[k*6+j];
            D[i*6+j] = s;
        }
}
DEVFN void inv6(const float* A, float* Ai) {    // Gauss-Jordan (no pivot; I+PSD*PSD)
    float M[6][12];
    #pragma unroll
    for (int i = 0; i < 6; ++i)
        #pragma unroll
        for (int j = 0; j < 6; ++j) {
            M[i][j]   = A[i*6+j];
            M[i][6+j] = (i == j) ? 1.f : 0.f;
        }
    #pragma unroll
    for (int c = 0; c < 6; ++c) {
        float piv = 1.f / M[c][c];
        #pragma unroll
        for (int j = 0; j < 12; ++j) M[c][j] *= piv;
        #pragma unroll
        for (int rr = 0; rr < 6; ++rr) {
            if (rr == c) continue;
            float f = M[rr][c];
            #pragma unroll
            for (int j = 0; j < 12; ++j) M[rr][j] -= f * M[c][j];
        }
    }
    #pragma unroll
    for (int i = 0; i < 6; ++i)
        #pragma unroll
        for (int j = 0; j < 6; ++j) Ai[i*6+j] = M[i][6+j];
}
DEVFN float inv4(const float* Y, float* Yi) {   // adjugate; returns det
    float m00=Y[0], m01=Y[1], m02=Y[2], m03=Y[3];
    float m10=Y[4], m11=Y[5], m12=Y[6], m13=Y[7];
    float m20=Y[8], m21=Y[9], m22=Y[10], m23=Y[11];
    float m30=Y[12], m31=Y[13], m32=Y[14], m33=Y[15];
    float s0 = m00*m11 - m10*m01;
    float s1 = m00*m12 - m10*m02;
    float s2 = m00*m13 - m10*m03;
    float s3 = m01*m12 - m11*m02;
    float s4 = m01*m13 - m11*m03;
    float s5 = m02*m13 - m12*m03;
    float c5 = m22*m33 - m32*m23;
    float c4 = m21*m33 - m31*m23;
    float c3 = m21*m32 - m31*m22;
    float c2 = m20*m33 - m30*m23;
    float c1 = m20*m32 - m30*m22;
    float c0 = m20*m31 - m30*m21;
    float det = s0*c5 - s1*c4 + s2*c3 + s3*c2 - s4*c1 + s5*c0;
    float inv = 1.0f / det;
    Yi[0]  = ( m11*c5 - m12*c4 + m13*c3) * inv;
    Yi[1]  = (-m01*c5 + m02*c4 - m03*c3) * inv;
    Yi[2]  = ( m31*s5 - m32*s4 + m33*s3) * inv;
    Yi[3]  = (-m21*s5 + m22*s4 - m23*s3) * inv;
    Yi[4]  = (-m10*c5 + m12*c2 - m13*c1) * inv;
    Yi[5]  = ( m00*c5 - m02*c2 + m03*c1) * inv;
    Yi[6]  = (-m30*s5 + m32*s2 - m33*s1) * inv;
    Yi[7]  = ( m20*s5 - m22*s2 + m23*s1) * inv;
    Yi[8]  = ( m10*c4 - m11*c2 + m13*c0) * inv;
    Yi[9]  = (-m00*c4 + m01*c2 - m03*c0) * inv;
    Yi[10] = ( m30*s4 - m31*s2 + m33*s0) * inv;
    Yi[11] = (-m20*s4 + m21*s2 - m23*s0) * inv;
    Yi[12] = (-m10*c3 + m11*c1 - m12*c0) * inv;
    Yi[13] = ( m00*c3 - m01*c1 + m02*c0) * inv;
    Yi[14] = (-m30*s3 + m31*s1 - m32*s0) * inv;
    Yi[15] = ( m20*s3 - m21*s1 + m22*s0) * inv;
    return det;
}

// ACJ-only Sarkka combine (round-1 combine6 minus b,e). Out must not alias in.
DEVFN void combine_acj(const float* A1, const float* C1, const float* J1,
                       const float* A2, const float* C2, const float* J2,
                       float* OA, float* OC, float* OJ)
{
    float T1[36], M[36], T2[36], T3[36];
    mul66(C1, J2, T1);
    #pragma unroll
    for (int i = 0; i < 6; ++i) T1[i*6+i] += 1.f;
    inv6(T1, M);                     // M = (I + C1 J2)^-1
    mul66(A2, M, T2);                // T2 = A2 M
    mul66(T2, A1, OA);               // A  = A2 M A1
    mul66(T2, C1, T3);               // T3 = A2 M C1
    mulT66(T3, A2, OC);              // C  = T3 A2^T + C2 (sym)
    #pragma unroll
    for (int i = 0; i < 6; ++i)
        #pragma unroll
        for (int j = 0; j <= i; ++j) {
            float v = 0.5f * (OC[i*6+j] + OC[j*6+i]) + 0.5f * (C2[i*6+j] + C2[j*6+i]);
            OC[i*6+j] = v; OC[j*6+i] = v;
        }
    tmul66(M, J2, T1);               // J = A1^T M^T J2 A1 + J1 (sym)
    tmul66(A1, T1, T3);
    mul66(T3, A1, OJ);
    #pragma unroll
    for (int i = 0; i < 6; ++i)
        #pragma unroll
        for (int j = 0; j <= i; ++j) {
            float v = 0.5f * (OJ[i*6+j] + OJ[j*6+i]) + 0.5f * (J1[i*6+j] + J1[j*6+i]);
            OJ[i*6+j] = v; OJ[j*6+i] = v;
        }
}

DEVFN void build_FHQ(float* F, float* H, float* Qm,
                     float A00, float A01, float A10, float A11, float sq, float q) {
    #pragma unroll
    for (int i = 0; i < 36; ++i) { F[i] = 0.f; Qm[i] = 0.f; }
    #pragma unroll
    for (int i = 0; i < 24; ++i) H[i] = 0.f;
    F[0*6+0] = 1.f; F[1*6+1] = 1.f; F[2*6+2] = 1.f; F[3*6+3] = 1.f;
    F[4*6+4] = A00; F[4*6+5] = A10; F[5*6+4] = A01; F[5*6+5] = A11;   // F_ss = A^T
    H[0*6+0] = 1.f; H[1*6+1] = 1.f; H[2*6+2] = 1.f; H[3*6+3] = 1.f;
    H[0*6+4] = sq;  H[1*6+4] = sq;  H[2*6+5] = sq;  H[3*6+5] = sq;
    Qm[4*6+4] = q;  Qm[5*6+5] = q;
}
DEVFN void build_P0(float* P, const float* bias_scales, const float* init_cov) {
    #pragma unroll
    for (int i = 0; i < 36; ++i) P[i] = 0.f;
    float b0 = bias_scales[0], b1 = bias_scales[1];
    P[0*6+0] = b0; P[1*6+1] = b1; P[2*6+2] = b0; P[3*6+3] = b1;
    P[4*6+4] = init_cov[0];
    float off = 0.5f * (init_cov[1] + init_cov[2]);
    P[4*6+5] = off; P[5*6+4] = off;
    P[5*6+5] = init_cov[3];
}

// TI leaf element (A,C,J) — round-1 formulas (verified)
DEVFN void build_leaf(float* lA, float* lC, float* lJ,
                      float A00, float A01, float A10, float A11,
                      float sq, float q, float r)
{
    float F[36], H[24], Qm[36];
    build_FHQ(F, H, Qm, A00, A01, A10, A11, sq, q);
    float HQ[24];
    for (int t = 0; t < 4; ++t)
        for (int j = 0; j < 6; ++j) {
            float s = 0.f;
            for (int k = 0; k < 6; ++k) s += H[t*6+k] * Qm[k*6+j];
            HQ[t*6+j] = s;
        }
    float Sm[16];
    for (int t = 0; t < 4; ++t)
        for (int u = 0; u < 4; ++u) {
            float s = 0.f;
            for (int j = 0; j < 6; ++j) s += HQ[t*6+j] * H[u*6+j];
            Sm[t*4+u] = s + ((t == u) ? r : 0.f);
        }
    float Si[16]; inv4(Sm, Si);
    float QHt[24];
    for (int i = 0; i < 6; ++i)
        for (int t = 0; t < 4; ++t) {
            float s = 0.f;
            for (int j = 0; j < 6; ++j) s += Qm[i*6+j] * H[t*6+j];
            QHt[i*4+t] = s;
        }
    float Kst[24];
    for (int i = 0; i < 6; ++i)
        for (int t = 0; t < 4; ++t) {
            float s = 0.f;
            for (int u = 0; u < 4; ++u) s += QHt[i*4+u] * Si[u*4+t];
            Kst[i*4+t] = s;
        }
    float HF[24];
    for (int t = 0; t < 4; ++t)
        for (int j = 0; j < 6; ++j) {
            float s = 0.f;
            for (int k = 0; k < 6; ++k) s += H[t*6+k] * F[k*6+j];
            HF[t*6+j] = s;
        }
    float Ct[36], Jt[36], Nst[24];
    for (int i = 0; i < 6; ++i)
        for (int j = 0; j < 6; ++j) {
            float s = 0.f;
            for (int t = 0; t < 4; ++t) s += Kst[i*4+t] * HF[t*6+j];
            lA[i*6+j] = F[i*6+j] - s;
            float s2 = 0.f;
            for (int t = 0; t < 4; ++t) s2 += Kst[i*4+t] * HQ[t*6+j];
            Ct[i*6+j] = Qm[i*6+j] - s2;
        }
    for (int i = 0; i < 6; ++i)
        for (int t = 0; t < 4; ++t) {
            float s = 0.f;
            for (int u = 0; u < 4; ++u) s += HF[u*6+i] * Si[u*4+t];
            Nst[i*4+t] = s;
        }
    for (int i = 0; i < 6; ++i)
        for (int j = 0; j < 6; ++j) {
            float s = 0.f;
            for (int t = 0; t < 4; ++t) s += Nst[i*4+t] * HF[t*6+j];
            Jt[i*6+j] = s;
        }
    for (int i = 0; i < 6; ++i)
        for (int j = 0; j < 6; ++j) {
            lC[i*6+j] = 0.5f * (Ct[i*6+j] + Ct[j*6+i]);
            lJ[i*6+j] = 0.5f * (Jt[i*6+j] + Jt[j*6+i]);
        }
}

// one cov-only KF step on P[6][6] (round-1 k_ll cov path)
DEVFN void cov_step(float P[6][6], float A00, float A01, float A10, float A11,
                    float sq, float q, float r)
{
    const int gof[4] = {0, 0, 1, 1};
    #pragma unroll
    for (int t = 0; t < 4; ++t) {
        float c4 = P[t][4], c5 = P[t][5];
        P[t][4] = c4*A00 + c5*A10;
        P[t][5] = c4*A01 + c5*A11;
    }
    {
        float p44 = P[4][4], p45 = P[4][5], p54 = P[5][4], p55 = P[5][5];
        float b00 = p44*A00 + p45*A10, b01 = p44*A01 + p45*A11;
        float b10 = p54*A00 + p55*A10, b11 = p54*A01 + p55*A11;
        float n44 = A00*b00 + A10*b10 + q;
        float n45 = A00*b01 + A10*b11;
        float n54 = A01*b00 + A11*b10;
        float n55 = A01*b01 + A11*b11 + q;
        float off = 0.5f * (n45 + n54);
        P[4][4] = n44; P[4][5] = off; P[5][4] = off; P[5][5] = n55;
    }
    #pragma unroll
    for (int t = 0; t < 4; ++t) { P[4][t] = P[t][4]; P[5][t] = P[t][5]; }

    float Hp[4][6];
    #pragma unroll
    for (int t = 0; t < 4; ++t) {
        const int gr = 4 + gof[t];
        #pragma unroll
        for (int j = 0; j < 6; ++j) Hp[t][j] = P[t][j] + sq * P[gr][j];
    }
    float Y[16];
    #pragma unroll
    for (int t = 0; t < 4; ++t)
        #pragma unroll
        for (int u = 0; u < 4; ++u) {
            float v = Hp[t][u] + sq * Hp[t][4+gof[u]];
            if (t == u) v += r;
            Y[t*4+u] = v;
        }
    float Yi[16];
    inv4(Y, Yi);
    float W[4][6];
    #pragma unroll
    for (int u = 0; u < 4; ++u)
        #pragma unroll
        for (int j = 0; j < 6; ++j)
            W[u][j] = Yi[u*4+0]*Hp[0][j] + Yi[u*4+1]*Hp[1][j]
                    + Yi[u*4+2]*Hp[2][j] + Yi[u*4+3]*Hp[3][j];
    #pragma unroll
    for (int j = 0; j < 6; ++j)
        #pragma unroll
        for (int l = j; l < 6; ++l) {
            float dv = Hp[0][j]*W[0][l] + Hp[1][j]*W[1][l]
                     + Hp[2][j]*W[2][l] + Hp[3][j]*W[3][l];
            float nv = P[j][l] - dv;
            P[j][l] = nv; P[l][j] = nv;
        }
}

// ---------------- K0: setup — leaf, doubling table, chunk0 cov ----------------
__launch_bounds__(128, 1)
__global__ void k_setup(const float* __restrict__ bias_scales,
                        const float* __restrict__ obs_noise,
                        const float* __restrict__ trans_noise,
                        const float* __restrict__ Amat,
                        const float* __restrict__ init_cov,
                        const int* __restrict__ num_sensors,
                        float* __restrict__ Dtab, float* __restrict__ C0f,
                        float* __restrict__ Btab)
{
    const int tid = (int)threadIdx.x;
    const float r = obs_noise[0]*obs_noise[0];
    const float q = trans_noise[0]*trans_noise[0];
    const int   S = num_sensors[0];
    const float sq = sqrtf((float)(S >> 1));
    const float A00 = Amat[0], A01 = Amat[1], A10 = Amat[2], A11 = Amat[3];

    if (tid == 64) {
        // chunk0: CHUNK cov-only steps from P0 (direct, proven path)
        float P0[36]; build_P0(P0, bias_scales, init_cov);
        float P[6][6];
        #pragma unroll
        for (int i = 0; i < 6; ++i)
            #pragma unroll
            for (int j = 0; j < 6; ++j) P[i][j] = P0[i*6+j];
        for (int i = 0; i < 36; ++i) Btab[i] = P0[i];
        for (int s = 0; s < CHUNK; ++s)
            cov_step(P, A00, A01, A10, A11, sq, q, r);
        #pragma unroll
        for (int i = 0; i < 6; ++i)
            #pragma unroll
            for (int j = 0; j < 6; ++j) {
                C0f[i*6+j] = P[i][j];
                Btab[36 + i*6+j] = P[i][j];
            }
    }
    if (tid == 0) {
        float cA[36], cC[36], cJ[36], nA[36], nC[36], nJ[36];
        build_leaf(cA, cC, cJ, A00, A01, A10, A11, sq, q, r);
        // squaring chain: TI^2,4,8,16(=D0),32(=D1)...2048(=D7)
        for (int st = 0; st < 11; ++st) {
            combine_acj(cA, cC, cJ, cA, cC, cJ, nA, nC, nJ);
            #pragma unroll
            for (int i = 0; i < 36; ++i) { cA[i] = nA[i]; cC[i] = nC[i]; cJ[i] = nJ[i]; }
            if (st >= 3) {
                float* D = Dtab + (size_t)(st - 3) * 108;
                for (int i = 0; i < 36; ++i) { D[i] = cA[i]; D[36+i] = cC[i]; D[72+i] = cJ[i]; }
            }
        }
    }
}

// ---------------- K1: boundary covariances (data-independent) ----------------
__launch_bounds__(64, 1)
__global__ void k_btab(const float* __restrict__ Dtab, const float* __restrict__ C0f,
                       float* __restrict__ Btab, int NCH)
{
    const int gid = (int)blockIdx.x * 64 + (int)threadIdx.x;
    if (gid > NCH || gid <= 1) return;   // 0,1 written by k_setup
    const int e = gid - 1;               // exponent of P16

    float aA[36], aC[36], aJ[36];
    bool first = true;
    for (int l = 0; l < 8; ++l) {
        if (!((e >> l) & 1)) continue;
        const float* D = Dtab + (size_t)l * 108;
        if (first) {
            #pragma unroll
            for (int i = 0; i < 36; ++i) { aA[i] = D[i]; aC[i] = D[36+i]; aJ[i] = D[72+i]; }
            first = false;
        } else {
            float oA[36], oC[36], oJ[36];
            combine_acj(aA, aC, aJ, D, D+36, D+72, oA, oC, oJ);
            #pragma unroll
            for (int i = 0; i < 36; ++i) { aA[i] = oA[i]; aC[i] = oC[i]; aJ[i] = oJ[i]; }
        }
    }
    // combine with chunk0 (A=0, C=C0f, J=0): B = A2 M C0f A2^T + C2
    float T1[36], M[36], V[36], U[36], B[36];
    mul66(C0f, aJ, T1);
    #pragma unroll
    for (int i = 0; i < 6; ++i) T1[i*6+i] += 1.f;
    inv6(T1, M);
    mul66(aA, M, V);
    mul66(V, C0f, U);
    mulT66(U, aA, B);
    float* dst = Btab + (size_t)gid * 36;
    #pragma unroll
    for (int i = 0; i < 6; ++i)
        #pragma unroll
        for (int j = 0; j < 6; ++j)
            dst[i*6+j] = 0.5f*(B[i*6+j] + B[j*6+i]) + 0.5f*(aC[i*6+j] + aC[j*6+i]);
}

// ---------------- K2: per-chunk affine maps (Phi, gamma) + gains ----------------
__launch_bounds__(64, 1)
__global__ void k_phigam(const float* __restrict__ track,
                         const float* __restrict__ obs_noise,
                         const float* __restrict__ trans_noise,
                         const float* __restrict__ Amat,
                         const int* __restrict__ num_sensors,
                         const float* __restrict__ Btab,
                         float* __restrict__ Phit, float* __restrict__ Gamt,
                         float* __restrict__ ldt, float* __restrict__ Kst,
                         float* __restrict__ Yit, int NCH)
{
    const int gid = (int)blockIdx.x * 64 + (int)threadIdx.x;
    if (gid >= NCH) return;
    const float r = obs_noise[0]*obs_noise[0];
    const float q = trans_noise[0]*trans_noise[0];
    const int   S = num_sensors[0];
    const float sq = sqrtf((float)(S >> 1));
    const float A00 = Amat[0], A01 = Amat[1], A10 = Amat[2], A11 = Amat[3];
    const int gof[4] = {0, 0, 1, 1};

    float P[6][6];
    {
        const float* b = Btab + (size_t)gid * 36;
        #pragma unroll
        for (int i = 0; i < 6; ++i)
            #pragma unroll
            for (int j = 0; j < 6; ++j) P[i][j] = b[i*6+j];
    }
    float Phi[36], gm[6];
    #pragma unroll
    for (int i = 0; i < 36; ++i) Phi[i] = 0.f;
    #pragma unroll
    for (int i = 0; i < 6; ++i) { Phi[i*6+i] = 1.f; gm[i] = 0.f; }
    float ldet = 0.f;
    const int t0 = gid * CHUNK;

    for (int s = 0; s < CHUNK; ++s) {
        // predict
        #pragma unroll
        for (int t = 0; t < 4; ++t) {
            float c4 = P[t][4], c5 = P[t][5];
            P[t][4] = c4*A00 + c5*A10;
            P[t][5] = c4*A01 + c5*A11;
        }
        {
            float p44 = P[4][4], p45 = P[4][5], p54 = P[5][4], p55 = P[5][5];
            float b00 = p44*A00 + p45*A10, b01 = p44*A01 + p45*A11;
            float b10 = p54*A00 + p55*A10, b11 = p54*A01 + p55*A11;
            float n44 = A00*b00 + A10*b10 + q;
            float n45 = A00*b01 + A10*b11;
            float n54 = A01*b00 + A11*b10;
            float n55 = A01*b01 + A11*b11 + q;
            float off = 0.5f * (n45 + n54);
            P[4][4] = n44; P[4][5] = off; P[5][4] = off; P[5][5] = n55;
        }
        #pragma unroll
        for (int t = 0; t < 4; ++t) { P[4][t] = P[t][4]; P[5][t] = P[t][5]; }

        float Hp[4][6];
        #pragma unroll
        for (int t = 0; t < 4; ++t) {
            const int gr = 4 + gof[t];
            #pragma unroll
            for (int j = 0; j < 6; ++j) Hp[t][j] = P[t][j] + sq * P[gr][j];
        }
        float Y[16];
        #pragma unroll
        for (int t = 0; t < 4; ++t)
            #pragma unroll
            for (int u = 0; u < 4; ++u) {
                float v = Hp[t][u] + sq * Hp[t][4+gof[u]];
                if (t == u) v += r;
                Y[t*4+u] = v;
            }
        float Yi[16];
        float det = inv4(Y, Yi);
        ldet += __logf(det);

        float K[24];    // K[j][t] = sum_u Hp[u][j] * Yi[u][t]
        #pragma unroll
        for (int j = 0; j < 6; ++j)
            #pragma unroll
            for (int t = 0; t < 4; ++t)
                K[j*4+t] = Hp[0][j]*Yi[0*4+t] + Hp[1][j]*Yi[1*4+t]
                         + Hp[2][j]*Yi[2*4+t] + Hp[3][j]*Yi[3*4+t];

        {   // store gains for the quad pass
            float* kd = Kst + ((size_t)(t0 + s)) * 24;
            #pragma unroll
            for (int i = 0; i < 24; ++i) kd[i] = K[i];
            float* yd = Yit + ((size_t)(t0 + s)) * 16;
            #pragma unroll
            for (int i = 0; i < 16; ++i) yd[i] = Yi[i];
        }

        // P update
        float W[4][6];
        #pragma unroll
        for (int u = 0; u < 4; ++u)
            #pragma unroll
            for (int j = 0; j < 6; ++j)
                W[u][j] = Yi[u*4+0]*Hp[0][j] + Yi[u*4+1]*Hp[1][j]
                        + Yi[u*4+2]*Hp[2][j] + Yi[u*4+3]*Hp[3][j];
        #pragma unroll
        for (int j = 0; j < 6; ++j)
            #pragma unroll
            for (int l = j; l < 6; ++l) {
                float dv = Hp[0][j]*W[0][l] + Hp[1][j]*W[1][l]
                         + Hp[2][j]*W[2][l] + Hp[3][j]*W[3][l];
                float nv = P[j][l] - dv;
                P[j][l] = nv; P[l][j] = nv;
            }

        // M_s = (I - K H) F ;  N = I - K H
        float N[36];
        #pragma unroll
        for (int j = 0; j < 6; ++j) {
            #pragma unroll
            for (int c = 0; c < 4; ++c) N[j*6+c] = -K[j*4+c];
            N[j*6+4] = -sq * (K[j*4+0] + K[j*4+1]);
            N[j*6+5] = -sq * (K[j*4+2] + K[j*4+3]);
            N[j*6+j] += 1.f;
        }
        float Ms[36];
        #pragma unroll
        for (int j = 0; j < 6; ++j) {
            #pragma unroll
            for (int c = 0; c < 4; ++c) Ms[j*6+c] = N[j*6+c];
            Ms[j*6+4] = N[j*6+4]*A00 + N[j*6+5]*A01;
            Ms[j*6+5] = N[j*6+4]*A10 + N[j*6+5]*A11;
        }
        // Phi <- Ms * Phi ; gm <- Ms*gm + K*y
        float Pn[36];
        mul66(Ms, Phi, Pn);
        #pragma unroll
        for (int i = 0; i < 36; ++i) Phi[i] = Pn[i];
        float x0 = track[2*(t0+s)], x1 = track[2*(t0+s)+1];
        float gn[6];
        #pragma unroll
        for (int i = 0; i < 6; ++i) {
            float sacc = 0.f;
            #pragma unroll
            for (int j = 0; j < 6; ++j) sacc += Ms[i*6+j] * gm[j];
            gn[i] = sacc + sq * ((K[i*4+0] + K[i*4+2]) * x0 + (K[i*4+1] + K[i*4+3]) * x1);
        }
        #pragma unroll
        for (int i = 0; i < 6; ++i) gm[i] = gn[i];
    }

    float* pd = Phit + (size_t)gid * 36;
    #pragma unroll
    for (int i = 0; i < 36; ++i) pd[i] = Phi[i];
    float* gd = Gamt + (size_t)gid * 6;
    #pragma unroll
    for (int i = 0; i < 6; ++i) gd[i] = gm[i];
    ldt[gid] = ldet;
}

// ---------------- K3: in-LDS affine scan + quad + reduce + scatter ----------------
__launch_bounds__(256, 1)
__global__ void k_scan_quad(const float* __restrict__ track,
                            const float* __restrict__ bias_scales,
                            const float* __restrict__ obs_noise,
                            const float* __restrict__ Amat,
                            const int* __restrict__ num_sensors,
                            const float* __restrict__ Phit, const float* __restrict__ Gamt,
                            const float* __restrict__ ldt, const float* __restrict__ Kst,
                            const float* __restrict__ Yit, const float* __restrict__ Btab,
                            float* __restrict__ out, int out_size, int T, int NCH)
{
    const int tid = (int)threadIdx.x;
    __shared__ float sE[256 * 44];       // [Phi(36) | gm(6) | pad]
    __shared__ double s_red[256];
    __shared__ double s_wc[256];
    __shared__ double s_Q[36];
    __shared__ double s_scal[2];

    const float A00 = Amat[0], A01 = Amat[1], A10 = Amat[2], A11 = Amat[3];
    const int   S  = num_sensors[0];
    const float sq = sqrtf((float)(S >> 1));
    const double r = (double)obs_noise[0] * (double)obs_noise[0];
    const int    n  = S >> 1;
    const double dn = (double)n;
    const double sqn = sqrt(dn);
    const double d0p0 = (double)bias_scales[0];
    const double d0p1 = (double)bias_scales[1];

    if (tid < NCH) {
        const float* p = Phit + (size_t)tid * 36;
        #pragma unroll
        for (int k = 0; k < 36; ++k) sE[tid*44 + k] = p[k];
        const float* g = Gamt + (size_t)tid * 6;
        #pragma unroll
        for (int k = 0; k < 6; ++k) sE[tid*44 + 36 + k] = g[k];
    }
    __syncthreads();

    for (int off = 1; off < NCH; off <<= 1) {
        float L[42], Sf[42];
        const bool act = (tid >= off) && (tid < NCH);
        if (act) {
            #pragma unroll
            for (int k = 0; k < 42; ++k) L[k]  = sE[(tid-off)*44 + k];
            #pragma unroll
            for (int k = 0; k < 42; ++k) Sf[k] = sE[tid*44 + k];
        }
        __syncthreads();
        if (act) {
            float nP[36];
            mul66(Sf, L, nP);            // Phi2 * Phi1
            #pragma unroll
            for (int k = 0; k < 36; ++k) sE[tid*44 + k] = nP[k];
            #pragma unroll
            for (int i = 0; i < 6; ++i) {
                float sacc = 0.f;
                #pragma unroll
                for (int j = 0; j < 6; ++j) sacc += Sf[i*6+j] * L[36+j];
                sE[tid*44 + 36 + i] = sacc + Sf[36+i];
            }
        }
        __syncthreads();
    }

    // ---- quad/loglik pass per chunk ----
    double partial = 0.0;
    if (tid < NCH) {
        float m[6];
        if (tid == 0) {
            #pragma unroll
            for (int i = 0; i < 6; ++i) m[i] = 0.f;
        } else {
            #pragma unroll
            for (int i = 0; i < 6; ++i) m[i] = sE[(tid-1)*44 + 36 + i];
        }
        float quad = 0.f;
        const int t0 = tid * CHUNK;
        for (int s = 0; s < CHUNK; ++s) {
            float a4 = A00*m[4] + A10*m[5];
            float a5 = A01*m[4] + A11*m[5];
            m[4] = a4; m[5] = a5;
            float x0 = track[2*(t0+s)], x1 = track[2*(t0+s)+1];
            float rv[4];
            rv[0] = sq*x0 - m[0] - sq*m[4];
            rv[1] = sq*x1 - m[1] - sq*m[4];
            rv[2] = sq*x0 - m[2] - sq*m[5];
            rv[3] = sq*x1 - m[3] - sq*m[5];
            const float* Yi = Yit + ((size_t)(t0 + s)) * 16;
            float al[4];
            #pragma unroll
            for (int t = 0; t < 4; ++t)
                al[t] = Yi[t*4+0]*rv[0] + Yi[t*4+1]*rv[1] + Yi[t*4+2]*rv[2] + Yi[t*4+3]*rv[3];
            quad += rv[0]*al[0] + rv[1]*al[1] + rv[2]*al[2] + rv[3]*al[3];
            const float* Kp = Kst + ((size_t)(t0 + s)) * 24;
            #pragma unroll
            for (int j = 0; j < 6; ++j)
                m[j] += Kp[j*4+0]*rv[0] + Kp[j*4+1]*rv[1] + Kp[j*4+2]*rv[2] + Kp[j*4+3]*rv[3];
        }
        partial = -0.5 * (4.0 * LOG2PI_D * (double)CHUNK + (double)quad)
                  - 0.5 * (double)ldt[tid];
    }
    s_red[tid] = partial;

    // within-class closed form (proven round-1 formulas)
    double wc = 0.0;
    for (int k = tid; k < T; k += 256) {
        double j  = (double)k;
        double c0 = d0p0 * r / (r + j * d0p0) + r;
        double c1 = d0p1 * r / (r + j * d0p1) + r;
        wc += (double)__logf((float)c0) + (double)__logf((float)c1);
    }
    s_wc[tid] = wc;

    if (tid == 0) {
        const float* PT = Btab + (size_t)NCH * 36;
        double MI[6][12];
        #pragma unroll
        for (int i = 0; i < 6; ++i)
            #pragma unroll
            for (int j = 0; j < 6; ++j) {
                MI[i][j]   = 0.5 * ((double)PT[i*6+j] + (double)PT[j*6+i]);
                MI[i][6+j] = (i == j) ? 1.0 : 0.0;
            }
        #pragma unroll
        for (int cc = 0; cc < 6; ++cc) {
            double piv = 1.0 / MI[cc][cc];
            #pragma unroll
            for (int j = 0; j < 12; ++j) MI[cc][j] *= piv;
            #pragma unroll
            for (int rr = 0; rr < 6; ++rr) {
                if (rr == cc) continue;
                double f = MI[rr][cc];
                #pragma unroll
                for (int j = 0; j < 12; ++j) MI[rr][j] -= f * MI[cc][j];
            }
        }
        #pragma unroll
        for (int i = 0; i < 6; ++i)
            #pragma unroll
            for (int j = 0; j < 6; ++j)
                s_Q[i*6+j] = 0.5 * (MI[i][6+j] + MI[j][6+i]);
        s_scal[0] = d0p0 * r / (r + (double)T * d0p0);
        s_scal[1] = d0p1 * r / (r + (double)T * d0p1);
    }
    __syncthreads();

    for (int s2 = 128; s2 > 0; s2 >>= 1) {
        if (tid < s2) {
            s_red[tid] += s_red[tid + s2];
            s_wc[tid]  += s_wc[tid + s2];
        }
        __syncthreads();
    }

    const double Lsum    = s_wc[0];
    const double ll_main = s_red[0];
    const double logp = ll_main - 2.0*(dn - 1.0)*LOG2PI_D*(double)T - (dn - 1.0)*Lsum;
    const double dTp0 = s_scal[0], dTp1 = s_scal[1];
    const double inv_sqn = 1.0 / sqn;
    const int D  = 2*S + 2;
    const int ob = D - 2;

    for (int idx = tid; idx < out_size; idx += 256) {
        double v;
        if (idx == 0) {
            v = logp;
        } else {
            int e = idx - 1;
            int row = e / D;
            int col = e - row * D;
            if (row < ob && col < ob) {
                int tr = ((row / S) << 1) | (row & 1);
                int tc = ((col / S) << 1) | (col & 1);
                v = s_Q[tr*6 + tc] / dn;
                if (tr == tc) {
                    double dt = (tr & 1) ? dTp1 : dTp0;
                    v -= 1.0 / (dn * dt);
                    if (row == col) v += 1.0 / dt;
                }
            } else if (row < ob) {
                int tr = ((row / S) << 1) | (row & 1);
                v = s_Q[tr*6 + 4 + (col - ob)] * inv_sqn;
            } else if (col < ob) {
                int tc = ((col / S) << 1) | (col & 1);
                v = s_Q[(4 + row - ob)*6 + tc] * inv_sqn;
            } else {
                v = s_Q[(4 + row - ob)*6 + (4 + col - ob)];
            }
        }
        out[idx] = (float)v;
    }
}

extern "C" void kernel_launch(void* const* d_in, const int* in_sizes, int n_in,
                              void* d_out, int out_size, void* d_ws, size_t ws_size,
                              hipStream_t stream) {
    const float* track        = (const float*)d_in[0];
    const float* bias_scales  = (const float*)d_in[1];
    const float* obs_noise    = (const float*)d_in[2];
    const float* trans_noise  = (const float*)d_in[3];
    const float* Amat         = (const float*)d_in[4];
    const float* init_cov     = (const float*)d_in[5];
    const int*   num_sensors  = (const int*)d_in[6];

    const int T   = in_sizes[0] / 2;     // 4096
    const int NCH = T / CHUNK;           // 256

    float* W    = (float*)d_ws;
    float* Dtab = W;                                  // 8*108
    float* C0f  = Dtab + 8*108;                       // 36
    float* Btab = C0f + 36;                           // (NCH+1)*36
    float* Phit = Btab + (size_t)(NCH+1)*36;          // NCH*36
    float* Gamt = Phit + (size_t)NCH*36;              // NCH*6
    float* ldt  = Gamt + (size_t)NCH*6;               // NCH
    float* Kst  = ldt  + NCH;                         // T*24
    float* Yit  = Kst  + (size_t)T*24;                // T*16

    k_setup<<<1, 128, 0, stream>>>(bias_scales, obs_noise, trans_noise, Amat,
                                   init_cov, num_sensors, Dtab, C0f, Btab);

    const int nb1 = (NCH + 1 + 63) / 64;
    k_btab<<<nb1, 64, 0, stream>>>(Dtab, C0f, Btab, NCH);

    const int nb2 = (NCH + 63) / 64;
    k_phigam<<<nb2, 64, 0, stream>>>(track, obs_noise, trans_noise, Amat, num_sensors,
                                     Btab, Phit, Gamt, ldt, Kst, Yit, NCH);

    k_scan_quad<<<1, 256, 0, stream>>>(track, bias_scales, obs_noise, Amat, num_sensors,
                                       Phit, Gamt, ldt, Kst, Yit, Btab,
                                       (float*)d_out, out_size, T, NCH);
}

// Round 7
// 111.831 us; speedup vs baseline: 34.9385x; 2.4056x over previous
//
#include <hip/hip_runtime.h>
#include <math.h>

// Two independent workgroups:
//   block 0: logp via the round-3 4-dim collapsed parallel KF (Output 0 PASSED) -> out[0]
//   block 1: precision via the round-2 HW-PROVEN 6-dim element algebra
//            (leaf -> bit-fold powers of TI -> prior fold -> f64 inverse -> scatter),
//            with each 6x6 op executed entry-parallel (36/72 threads) -> out[1..]

#define LOG2PI_D 1.8378770664093454
#define CHUNK 16
#define DEVFN __device__ __forceinline__

// ================= 4x4 helpers (block-0 logp path, round-3 verbatim) =========
DEVFN void mul44(const float* A, const float* B, float* D) {
    #pragma unroll
    for (int i = 0; i < 4; ++i)
        #pragma unroll
        for (int j = 0; j < 4; ++j) {
            float s = 0.f;
            #pragma unroll
            for (int k = 0; k < 4; ++k) s += A[i*4+k] * B[k*4+j];
            D[i*4+j] = s;
        }
}
DEVFN void mulT44(const float* A, const float* B, float* D) {
    #pragma unroll
    for (int i = 0; i < 4; ++i)
        #pragma unroll
        for (int j = 0; j < 4; ++j) {
            float s = 0.f;
            #pragma unroll
            for (int k = 0; k < 4; ++k) s += A[i*4+k] * B[j*4+k];
            D[i*4+j] = s;
        }
}
DEVFN void tmul44(const float* A, const float* B, float* D) {
    #pragma unroll
    for (int i = 0; i < 4; ++i)
        #pragma unroll
        for (int j = 0; j < 4; ++j) {
            float s = 0.f;
            #pragma unroll
            for (int k = 0; k < 4; ++k) s += A[k*4+i] * B[k*4+j];
            D[i*4+j] = s;
        }
}
DEVFN float inv4f(const float* Y, float* Yi) {
    float m00=Y[0], m01=Y[1], m02=Y[2], m03=Y[3];
    float m10=Y[4], m11=Y[5], m12=Y[6], m13=Y[7];
    float m20=Y[8], m21=Y[9], m22=Y[10], m23=Y[11];
    float m30=Y[12], m31=Y[13], m32=Y[14], m33=Y[15];
    float s0 = m00*m11 - m10*m01;
    float s1 = m00*m12 - m10*m02;
    float s2 = m00*m13 - m10*m03;
    float s3 = m01*m12 - m11*m02;
    float s4 = m01*m13 - m11*m03;
    float s5 = m02*m13 - m12*m03;
    float c5 = m22*m33 - m32*m23;
    float c4 = m21*m33 - m31*m23;
    float c3 = m21*m32 - m31*m22;
    float c2 = m20*m33 - m30*m23;
    float c1 = m20*m32 - m30*m22;
    float c0 = m20*m31 - m30*m21;
    float det = s0*c5 - s1*c4 + s2*c3 + s3*c2 - s4*c1 + s5*c0;
    float inv = 1.0f / det;
    Yi[0]  = ( m11*c5 - m12*c4 + m13*c3) * inv;
    Yi[1]  = (-m01*c5 + m02*c4 - m03*c3) * inv;
    Yi[2]  = ( m31*s5 - m32*s4 + m33*s3) * inv;
    Yi[3]  = (-m21*s5 + m22*s4 - m23*s3) * inv;
    Yi[4]  = (-m10*c5 + m12*c2 - m13*c1) * inv;
    Yi[5]  = ( m00*c5 - m02*c2 + m03*c1) * inv;
    Yi[6]  = (-m30*s5 + m32*s2 - m33*s1) * inv;
    Yi[7]  = ( m20*s5 - m22*s2 + m23*s1) * inv;
    Yi[8]  = ( m10*c4 - m11*c2 + m13*c0) * inv;
    Yi[9]  = (-m00*c4 + m01*c2 - m03*c0) * inv;
    Yi[10] = ( m30*s4 - m31*s2 + m33*s0) * inv;
    Yi[11] = (-m20*s4 + m21*s2 - m23*s0) * inv;
    Yi[12] = (-m10*c3 + m11*c1 - m12*c0) * inv;
    Yi[13] = ( m00*c3 - m01*c1 + m02*c0) * inv;
    Yi[14] = (-m30*s3 + m31*s1 - m32*s0) * inv;
    Yi[15] = ( m20*s3 - m21*s1 + m22*s0) * inv;
    return det;
}
DEVFN void combine4(const float* A1, const float* C1, const float* J1,
                    const float* A2, const float* C2, const float* J2,
                    float* OA, float* OC, float* OJ)
{
    float T1[16], M[16], T2[16], T3[16];
    mul44(C1, J2, T1);
    T1[0] += 1.f; T1[5] += 1.f; T1[10] += 1.f; T1[15] += 1.f;
    inv4f(T1, M);
    mul44(A2, M, T2);
    mul44(T2, A1, OA);
    mul44(T2, C1, T3);
    mulT44(T3, A2, OC);
    #pragma unroll
    for (int i = 0; i < 4; ++i)
        #pragma unroll
        for (int j = 0; j <= i; ++j) {
            float v = 0.5f*(OC[i*4+j]+OC[j*4+i]) + 0.5f*(C2[i*4+j]+C2[j*4+i]);
            OC[i*4+j] = v; OC[j*4+i] = v;
        }
    tmul44(M, J2, T1);
    tmul44(A1, T1, T3);
    mul44(T3, A1, OJ);
    #pragma unroll
    for (int i = 0; i < 4; ++i)
        #pragma unroll
        for (int j = 0; j <= i; ++j) {
            float v = 0.5f*(OJ[i*4+j]+OJ[j*4+i]) + 0.5f*(J1[i*4+j]+J1[j*4+i]);
            OJ[i*4+j] = v; OJ[j*4+i] = v;
        }
}

// ================= 6-dim serial builders (round-2 proven, unrolled) ==========
DEVFN void build_P06(float* P, const float* bias_scales, const float* init_cov) {
    #pragma unroll
    for (int i = 0; i < 36; ++i) P[i] = 0.f;
    float b0 = bias_scales[0], b1 = bias_scales[1];
    P[0*6+0] = b0; P[1*6+1] = b1; P[2*6+2] = b0; P[3*6+3] = b1;
    P[4*6+4] = init_cov[0];
    float off = 0.5f * (init_cov[1] + init_cov[2]);
    P[4*6+5] = off; P[5*6+4] = off;
    P[5*6+5] = init_cov[3];
}
DEVFN void build_leaf6(float* lA, float* lC, float* lJ,
                       float A00, float A01, float A10, float A11,
                       float sq, float q, float r)
{
    float F[36], H[24], Qm[36];
    #pragma unroll
    for (int i = 0; i < 36; ++i) { F[i] = 0.f; Qm[i] = 0.f; }
    #pragma unroll
    for (int i = 0; i < 24; ++i) H[i] = 0.f;
    F[0*6+0] = 1.f; F[1*6+1] = 1.f; F[2*6+2] = 1.f; F[3*6+3] = 1.f;
    F[4*6+4] = A00; F[4*6+5] = A10; F[5*6+4] = A01; F[5*6+5] = A11;
    H[0*6+0] = 1.f; H[1*6+1] = 1.f; H[2*6+2] = 1.f; H[3*6+3] = 1.f;
    H[0*6+4] = sq;  H[1*6+4] = sq;  H[2*6+5] = sq;  H[3*6+5] = sq;
    Qm[4*6+4] = q;  Qm[5*6+5] = q;

    float HQ[24];
    #pragma unroll
    for (int t = 0; t < 4; ++t)
        #pragma unroll
        for (int j = 0; j < 6; ++j) {
            float s = 0.f;
            #pragma unroll
            for (int k = 0; k < 6; ++k) s += H[t*6+k] * Qm[k*6+j];
            HQ[t*6+j] = s;
        }
    float Sm[16];
    #pragma unroll
    for (int t = 0; t < 4; ++t)
        #pragma unroll
        for (int u = 0; u < 4; ++u) {
            float s = 0.f;
            #pragma unroll
            for (int j = 0; j < 6; ++j) s += HQ[t*6+j] * H[u*6+j];
            Sm[t*4+u] = s + ((t == u) ? r : 0.f);
        }
    float Si[16]; inv4f(Sm, Si);
    float QHt[24];
    #pragma unroll
    for (int i = 0; i < 6; ++i)
        #pragma unroll
        for (int t = 0; t < 4; ++t) {
            float s = 0.f;
            #pragma unroll
            for (int j = 0; j < 6; ++j) s += Qm[i*6+j] * H[t*6+j];
            QHt[i*4+t] = s;
        }
    float Kst[24];
    #pragma unroll
    for (int i = 0; i < 6; ++i)
        #pragma unroll
        for (int t = 0; t < 4; ++t) {
            float s = 0.f;
            #pragma unroll
            for (int u = 0; u < 4; ++u) s += QHt[i*4+u] * Si[u*4+t];
            Kst[i*4+t] = s;
        }
    float HF[24];
    #pragma unroll
    for (int t = 0; t < 4; ++t)
        #pragma unroll
        for (int j = 0; j < 6; ++j) {
            float s = 0.f;
            #pragma unroll
            for (int k = 0; k < 6; ++k) s += H[t*6+k] * F[k*6+j];
            HF[t*6+j] = s;
        }
    float Ct[36], Jt[36], Nst[24];
    #pragma unroll
    for (int i = 0; i < 6; ++i)
        #pragma unroll
        for (int j = 0; j < 6; ++j) {
            float s = 0.f;
            #pragma unroll
            for (int t = 0; t < 4; ++t) s += Kst[i*4+t] * HF[t*6+j];
            lA[i*6+j] = F[i*6+j] - s;
            float s2 = 0.f;
            #pragma unroll
            for (int t = 0; t < 4; ++t) s2 += Kst[i*4+t] * HQ[t*6+j];
            Ct[i*6+j] = Qm[i*6+j] - s2;
        }
    #pragma unroll
    for (int i = 0; i < 6; ++i)
        #pragma unroll
        for (int t = 0; t < 4; ++t) {
            float s = 0.f;
            #pragma unroll
            for (int u = 0; u < 4; ++u) s += HF[u*6+i] * Si[u*4+t];
            Nst[i*4+t] = s;
        }
    #pragma unroll
    for (int i = 0; i < 6; ++i)
        #pragma unroll
        for (int j = 0; j < 6; ++j) {
            float s = 0.f;
            #pragma unroll
            for (int t = 0; t < 4; ++t) s += Nst[i*4+t] * HF[t*6+j];
            Jt[i*6+j] = s;
        }
    #pragma unroll
    for (int i = 0; i < 6; ++i)
        #pragma unroll
        for (int j = 0; j < 6; ++j) {
            lC[i*6+j] = 0.5f * (Ct[i*6+j] + Ct[j*6+i]);
            lJ[i*6+j] = 0.5f * (Jt[i*6+j] + Jt[j*6+i]);
        }
}

// ================= entry-parallel 6x6 primitives (block 1) ===================
// All helpers are called by ALL 256 threads of block 1 (uniform control flow).
DEVFN void pmul6(int tid, const float* X, const float* Y, float* D) {
    if (tid < 36) {
        int i = tid / 6, j = tid % 6;
        float s = 0.f;
        #pragma unroll
        for (int k = 0; k < 6; ++k) s += X[i*6+k] * Y[k*6+j];
        D[tid] = s;
    }
    __syncthreads();
}
DEVFN void pmulT6(int tid, const float* X, const float* Y, float* D) {   // X*Y^T
    if (tid < 36) {
        int i = tid / 6, j = tid % 6;
        float s = 0.f;
        #pragma unroll
        for (int k = 0; k < 6; ++k) s += X[i*6+k] * Y[j*6+k];
        D[tid] = s;
    }
    __syncthreads();
}
DEVFN void ptmul6(int tid, const float* X, const float* Y, float* D) {   // X^T*Y
    if (tid < 36) {
        int i = tid / 6, j = tid % 6;
        float s = 0.f;
        #pragma unroll
        for (int k = 0; k < 6; ++k) s += X[k*6+i] * Y[k*6+j];
        D[tid] = s;
    }
    __syncthreads();
}
DEVFN void pinv6p(int tid, const float* IN, float* M, float* aug, float* piv) {
    if (tid < 72) {
        int i = tid / 12, j = tid % 12;
        aug[tid] = (j < 6) ? IN[i*6+j] : ((j - 6 == i) ? 1.f : 0.f);
    }
    __syncthreads();
    for (int c = 0; c < 6; ++c) {
        if (tid == 0) piv[0] = 1.f / aug[c*12+c];
        __syncthreads();
        if (tid < 12) aug[c*12+tid] *= piv[0];
        __syncthreads();
        float f = 0.f;
        if (tid < 72) f = aug[(tid/12)*12 + c];
        __syncthreads();
        if (tid < 72) {
            int i = tid / 12, j = tid % 12;
            if (i != c) aug[i*12+j] -= f * aug[c*12+j];
        }
        __syncthreads();
    }
    if (tid < 36) {
        int i = tid / 6, j = tid % 6;
        M[tid] = aug[i*12 + 6 + j];
    }
    __syncthreads();
}
DEVFN void pcopy(int tid, const float* s, float* d, int n) {
    if (tid < n) d[tid] = s[tid];
    __syncthreads();
}
// Sarkka ACJ combine (1=earlier, 2=later), math verbatim from round-2 combine_acj.
DEVFN void pcombine6(int tid, const float* e1, const float* e2, float* eo,
                     float* sW, float* sM, float* sT2, float* sT4,
                     float* aug, float* piv)
{
    const float *A1 = e1, *C1 = e1+36, *J1 = e1+72;
    const float *A2 = e2, *C2 = e2+36, *J2 = e2+72;
    pmul6(tid, C1, J2, sW);                     // W = C1*J2
    if (tid < 6) sW[tid*6+tid] += 1.f;          // + I
    __syncthreads();
    pinv6p(tid, sW, sM, aug, piv);              // M = (I + C1 J2)^-1
    pmul6(tid, A2, sM, sT2);                    // T2 = A2 M
    pmul6(tid, sT2, A1, eo);                    // OA = T2 A1
    pmul6(tid, sT2, C1, sW);                    // W = T2 C1
    pmulT6(tid, sW, A2, sT4);                   // T4 = W A2^T
    if (tid < 36) {
        int i = tid / 6, j = tid % 6;
        eo[36+tid] = 0.5f*(sT4[i*6+j]+sT4[j*6+i]) + 0.5f*(C2[i*6+j]+C2[j*6+i]);
    }
    __syncthreads();
    ptmul6(tid, sM, J2, sT4);                   // T4 = M^T J2
    ptmul6(tid, A1, sT4, sW);                   // W = A1^T T4
    pmul6(tid, sW, A1, sT4);                    // T4 = W A1
    if (tid < 36) {
        int i = tid / 6, j = tid % 6;
        eo[72+tid] = 0.5f*(sT4[i*6+j]+sT4[j*6+i]) + 0.5f*(J1[i*6+j]+J1[j*6+i]);
    }
    __syncthreads();
}

// =============================== kernel ======================================
__launch_bounds__(256, 1)
__global__ void k_all(const float* __restrict__ track,
                      const float* __restrict__ bias_scales,
                      const float* __restrict__ obs_noise,
                      const float* __restrict__ trans_noise,
                      const float* __restrict__ Amat,
                      const float* __restrict__ init_cov,
                      const int* __restrict__ num_sensors,
                      float* __restrict__ out, int out_size, int T)
{
    const int tid = (int)threadIdx.x;
    // block-0 LDS
    __shared__ float  sE[256 * 21];
    __shared__ float  sD[256];
    __shared__ double s_red[256];
    // block-1 LDS
    __shared__ float  eCur[108], eAcc[108], eTmp[108];
    __shared__ float  sP0[36], sPT6[36];
    __shared__ float  sW[36], sM[36], sT2[36], sT4[36];
    __shared__ float  aug[72], piv[2];
    __shared__ double sQd[36], sSc[2];

    const float r   = obs_noise[0] * obs_noise[0];
    const float q   = trans_noise[0] * trans_noise[0];
    const int   S   = num_sensors[0];
    const int   n   = S >> 1;
    const float sq6 = sqrtf((float)n);          // 4 : class-mean coupling (6-dim model)
    const float A00 = Amat[0], A01 = Amat[1], A10 = Amat[2], A11 = Amat[3];
    const float d0p0 = bias_scales[0], d0p1 = bias_scales[1];
    const double dn = (double)n;

    if (blockIdx.x == 0) {
        // =================== BLOCK 0 : logp (round-3 path, PASSED) ===========
        const float c  = sq6 * 1.41421356237f;
        const float zc = sq6 * 0.70710678118f;
        const float dp = 0.5f * (d0p0 + d0p1);
        const float rinv = 1.f / r;
        const int NCH = (T + CHUNK - 1) / CHUNK;

        // Phase A: closed-form 4-dim TI leaf, 4 squarings -> E = TI^16
        float eA[16], eC[16], eJ[16];
        {
            const float c2v  = c * c;
            const float spsi = c2v * q + r;
            const float kk   = c * q / spsi;
            const float omk  = 1.f - kk * c;
            const float isp  = 1.f / spsi;
            #pragma unroll
            for (int i = 0; i < 16; ++i) { eA[i] = 0.f; eC[i] = 0.f; }
            eA[0] = 1.f; eA[5] = 1.f;
            eA[8]  = -kk; eA[10] = A00 * omk; eA[11] = A10 * omk;
            eA[13] = -kk; eA[14] = A01 * omk; eA[15] = A11 * omk;
            eC[10] = q * omk; eC[15] = q * omk;
            eJ[0] = isp; eJ[1] = 0.f; eJ[2] = c*A00*isp; eJ[3] = c*A10*isp;
            eJ[5] = isp; eJ[6] = c*A01*isp; eJ[7] = c*A11*isp;
            eJ[10] = c2v*(A00*A00 + A01*A01)*isp;
            eJ[11] = c2v*(A00*A10 + A01*A11)*isp;
            eJ[15] = c2v*(A10*A10 + A11*A11)*isp;
            eJ[4] = eJ[1]; eJ[8] = eJ[2]; eJ[12] = eJ[3];
            eJ[9] = eJ[6]; eJ[13] = eJ[7]; eJ[14] = eJ[11];
            #pragma unroll
            for (int s = 0; s < 4; ++s) {
                float nA[16], nC[16], nJ[16];
                combine4(eA, eC, eJ, eA, eC, eJ, nA, nC, nJ);
                #pragma unroll
                for (int i = 0; i < 16; ++i) { eA[i] = nA[i]; eC[i] = nC[i]; eJ[i] = nJ[i]; }
            }
        }
        // Phase B: B = prior o E^tid via binary powers
        float P04[16];
        {
            #pragma unroll
            for (int i = 0; i < 16; ++i) P04[i] = 0.f;
            P04[0] = dp; P04[5] = dp;
            P04[10] = init_cov[0];
            float off = 0.5f * (init_cov[1] + init_cov[2]);
            P04[11] = off; P04[14] = off;
            P04[15] = init_cov[3];
        }
        float B[16];
        {
            float aA[16], aC[16], aJ[16];
            bool first = true;
            const int e = tid;
            for (int l = 0; l < 8; ++l) {
                if (e & (1 << l)) {
                    if (first) {
                        #pragma unroll
                        for (int i = 0; i < 16; ++i) { aA[i] = eA[i]; aC[i] = eC[i]; aJ[i] = eJ[i]; }
                        first = false;
                    } else {
                        float oA[16], oC[16], oJ[16];
                        combine4(aA, aC, aJ, eA, eC, eJ, oA, oC, oJ);
                        #pragma unroll
                        for (int i = 0; i < 16; ++i) { aA[i] = oA[i]; aC[i] = oC[i]; aJ[i] = oJ[i]; }
                    }
                }
                if (l < 7) {
                    float oA[16], oC[16], oJ[16];
                    combine4(eA, eC, eJ, eA, eC, eJ, oA, oC, oJ);
                    #pragma unroll
                    for (int i = 0; i < 16; ++i) { eA[i] = oA[i]; eC[i] = oC[i]; eJ[i] = oJ[i]; }
                }
            }
            if (first) {
                #pragma unroll
                for (int i = 0; i < 16; ++i) B[i] = P04[i];
            } else {
                float T1[16], M4[16], T2[16], T3[16], Bt[16];
                mul44(P04, aJ, T1);
                T1[0] += 1.f; T1[5] += 1.f; T1[10] += 1.f; T1[15] += 1.f;
                inv4f(T1, M4);
                mul44(aA, M4, T2);
                mul44(T2, P04, T3);
                mulT44(T3, aA, Bt);
                #pragma unroll
                for (int i = 0; i < 4; ++i)
                    #pragma unroll
                    for (int j = 0; j < 4; ++j)
                        B[i*4+j] = 0.5f*(Bt[i*4+j]+Bt[j*4+i]) + 0.5f*(aC[i*4+j]+aC[j*4+i]);
            }
        }
        // Phase C: per-chunk cov pass -> Phi, gm, ldet, dsum
        const bool active = (tid < NCH);
        const int t0 = tid * CHUNK;
        float Phi[16], gm[4];
        #pragma unroll
        for (int i = 0; i < 16; ++i) Phi[i] = 0.f;
        Phi[0] = Phi[5] = Phi[10] = Phi[15] = 1.f;
        #pragma unroll
        for (int i = 0; i < 4; ++i) gm[i] = 0.f;
        float ldet = 0.f, dsum = 0.f;
        const float2* trk = (const float2*)track;

        if (active) {
            float P[16];
            #pragma unroll
            for (int i = 0; i < 16; ++i) P[i] = B[i];
            for (int s = 0; s < CHUNK; ++s) {
                const int t = t0 + s;
                if (t >= T) break;
                #pragma unroll
                for (int tt = 0; tt < 2; ++tt) {
                    float c2_ = P[tt*4+2], c3_ = P[tt*4+3];
                    P[tt*4+2] = c2_*A00 + c3_*A10;
                    P[tt*4+3] = c2_*A01 + c3_*A11;
                }
                {
                    float p22=P[10], p23=P[11], p32=P[14], p33=P[15];
                    float b00 = p22*A00 + p23*A10, b01 = p22*A01 + p23*A11;
                    float b10 = p32*A00 + p33*A10, b11 = p32*A01 + p33*A11;
                    float n22 = A00*b00 + A10*b10 + q;
                    float n23 = A00*b01 + A10*b11;
                    float n32 = A01*b00 + A11*b10;
                    float n33 = A01*b01 + A11*b11 + q;
                    float off = 0.5f*(n23+n32);
                    P[10]=n22; P[11]=off; P[14]=off; P[15]=n33;
                }
                P[8]=P[2]; P[9]=P[6]; P[12]=P[3]; P[13]=P[7];
                float Hp0[4], Hp1[4];
                #pragma unroll
                for (int j = 0; j < 4; ++j) { Hp0[j] = P[0*4+j] + c*P[2*4+j]; Hp1[j] = P[1*4+j] + c*P[3*4+j]; }
                float Y00 = Hp0[0] + c*Hp0[2] + r;
                float Y01 = Hp0[1] + c*Hp0[3];
                float Y11 = Hp1[1] + c*Hp1[3];
                float det = Y00*Y11 - Y01*Y01;
                ldet += __logf(det);
                float idet = 1.f/det;
                float Yi00 = Y11*idet, Yi01 = -Y01*idet, Yi11 = Y00*idet;
                float K0[4], K1[4];
                #pragma unroll
                for (int j = 0; j < 4; ++j) {
                    K0[j] = Hp0[j]*Yi00 + Hp1[j]*Yi01;
                    K1[j] = Hp0[j]*Yi01 + Hp1[j]*Yi11;
                }
                #pragma unroll
                for (int j = 0; j < 4; ++j)
                    #pragma unroll
                    for (int l = j; l < 4; ++l) {
                        float nv = P[j*4+l] - (K0[j]*Hp0[l] + K1[j]*Hp1[l]);
                        P[j*4+l] = nv; P[l*4+j] = nv;
                    }
                float Ms[16];
                #pragma unroll
                for (int j = 0; j < 4; ++j) {
                    float N0 = -K0[j] + ((j==0)?1.f:0.f);
                    float N1 = -K1[j] + ((j==1)?1.f:0.f);
                    float N2 = -c*K0[j] + ((j==2)?1.f:0.f);
                    float N3 = -c*K1[j] + ((j==3)?1.f:0.f);
                    Ms[j*4+0] = N0; Ms[j*4+1] = N1;
                    Ms[j*4+2] = N2*A00 + N3*A01;
                    Ms[j*4+3] = N2*A10 + N3*A11;
                }
                float Pn[16];
                mul44(Ms, Phi, Pn);
                #pragma unroll
                for (int i = 0; i < 16; ++i) Phi[i] = Pn[i];
                float2 xk = trk[t];
                float z = zc*(xk.x + xk.y);
                float d = zc*(xk.x - xk.y);
                dsum += d;
                float gn[4];
                #pragma unroll
                for (int i = 0; i < 4; ++i) {
                    float sacc = Ms[i*4+0]*gm[0] + Ms[i*4+1]*gm[1] + Ms[i*4+2]*gm[2] + Ms[i*4+3]*gm[3];
                    gn[i] = sacc + (K0[i] + K1[i]) * z;
                }
                #pragma unroll
                for (int i = 0; i < 4; ++i) gm[i] = gn[i];
            }
        }
        {
            float* dst = &sE[tid*21];
            #pragma unroll
            for (int k = 0; k < 16; ++k) dst[k] = Phi[k];
            #pragma unroll
            for (int k = 0; k < 4; ++k) dst[16+k] = gm[k];
            sD[tid] = dsum;
        }
        __syncthreads();

        // affine scan + d prefix
        for (int off = 1; off < NCH; off <<= 1) {
            float L[20]; float lsd = 0.f;
            const bool act = (tid >= off) && (tid < NCH);
            if (act) {
                const float* ls = &sE[(tid-off)*21];
                #pragma unroll
                for (int k = 0; k < 20; ++k) L[k] = ls[k];
                lsd = sD[tid-off];
            }
            __syncthreads();
            if (act) {
                float nP[16];
                mul44(Phi, L, nP);
                float ng[4];
                #pragma unroll
                for (int i = 0; i < 4; ++i)
                    ng[i] = Phi[i*4+0]*L[16] + Phi[i*4+1]*L[17] + Phi[i*4+2]*L[18] + Phi[i*4+3]*L[19] + gm[i];
                #pragma unroll
                for (int i = 0; i < 16; ++i) Phi[i] = nP[i];
                #pragma unroll
                for (int i = 0; i < 4; ++i) gm[i] = ng[i];
                dsum += lsd;
                float* dst = &sE[tid*21];
                #pragma unroll
                for (int k = 0; k < 16; ++k) dst[k] = Phi[k];
                #pragma unroll
                for (int k = 0; k < 4; ++k) dst[16+k] = gm[k];
                sD[tid] = dsum;
            }
            __syncthreads();
        }

        // Phase D: re-run chunks with means; all log-lik terms
        double partial = 0.0;
        if (active) {
            float m[4];
            if (tid == 0) { m[0]=m[1]=m[2]=m[3]=0.f; }
            else {
                const float* ls = &sE[(tid-1)*21];
                #pragma unroll
                for (int i = 0; i < 4; ++i) m[i] = ls[16+i];
            }
            float Srun = (tid == 0) ? 0.f : sD[tid-1];
            float P[16];
            #pragma unroll
            for (int i = 0; i < 16; ++i) P[i] = B[i];
            float quad = 0.f, qm_sum = 0.f, lm_sum = 0.f, wsum = 0.f;
            int ns = 0;
            for (int s = 0; s < CHUNK; ++s) {
                const int t = t0 + s;
                if (t >= T) break;
                ns++;
                {
                    float m2 = A00*m[2] + A10*m[3];
                    float m3 = A01*m[2] + A11*m[3];
                    m[2] = m2; m[3] = m3;
                }
                #pragma unroll
                for (int tt = 0; tt < 2; ++tt) {
                    float c2_ = P[tt*4+2], c3_ = P[tt*4+3];
                    P[tt*4+2] = c2_*A00 + c3_*A10;
                    P[tt*4+3] = c2_*A01 + c3_*A11;
                }
                {
                    float p22=P[10], p23=P[11], p32=P[14], p33=P[15];
                    float b00 = p22*A00 + p23*A10, b01 = p22*A01 + p23*A11;
                    float b10 = p32*A00 + p33*A10, b11 = p32*A01 + p33*A11;
                    float n22 = A00*b00 + A10*b10 + q;
                    float n23 = A00*b01 + A10*b11;
                    float n32 = A01*b00 + A11*b10;
                    float n33 = A01*b01 + A11*b11 + q;
                    float off = 0.5f*(n23+n32);
                    P[10]=n22; P[11]=off; P[14]=off; P[15]=n33;
                }
                P[8]=P[2]; P[9]=P[6]; P[12]=P[3]; P[13]=P[7];
                float Hp0[4], Hp1[4];
                #pragma unroll
                for (int j = 0; j < 4; ++j) { Hp0[j] = P[0*4+j] + c*P[2*4+j]; Hp1[j] = P[1*4+j] + c*P[3*4+j]; }
                float Y00 = Hp0[0] + c*Hp0[2] + r;
                float Y01 = Hp0[1] + c*Hp0[3];
                float Y11 = Hp1[1] + c*Hp1[3];
                float det = Y00*Y11 - Y01*Y01;
                float idet = 1.f/det;
                float Yi00 = Y11*idet, Yi01 = -Y01*idet, Yi11 = Y00*idet;
                float2 xk = trk[t];
                float z = zc*(xk.x + xk.y);
                float d = zc*(xk.x - xk.y);
                float r0 = z - m[0] - c*m[2];
                float r1 = z - m[1] - c*m[3];
                quad += r0*r0*Yi00 + 2.f*r0*r1*Yi01 + r1*r1*Yi11;
                float K0[4], K1[4];
                #pragma unroll
                for (int j = 0; j < 4; ++j) {
                    K0[j] = Hp0[j]*Yi00 + Hp1[j]*Yi01;
                    K1[j] = Hp0[j]*Yi01 + Hp1[j]*Yi11;
                }
                #pragma unroll
                for (int j = 0; j < 4; ++j) m[j] += K0[j]*r0 + K1[j]*r1;
                #pragma unroll
                for (int j = 0; j < 4; ++j)
                    #pragma unroll
                    for (int l = j; l < 4; ++l) {
                        float nv = P[j*4+l] - (K0[j]*Hp0[l] + K1[j]*Hp1[l]);
                        P[j*4+l] = nv; P[l*4+j] = nv;
                    }
                float tf = (float)t;
                float vj = dp*r / (r + tf*dp);
                float pre = vj + r;
                float ipre = 1.f/pre;
                float mm = vj * Srun * rinv;
                float dd = d - mm;
                qm_sum += dd*dd*ipre;
                lm_sum += __logf(pre);
                Srun += d;
                float c0 = d0p0*r / (r + tf*d0p0) + r;
                float c1 = d0p1*r / (r + tf*d0p1) + r;
                wsum += __logf(c0) + __logf(c1);
            }
            partial = -0.5*(2.0*LOG2PI_D*(double)ns + (double)quad + (double)ldet)
                      - (LOG2PI_D*(double)ns + (double)qm_sum + (double)lm_sum)
                      - (dn - 1.0)*(2.0*LOG2PI_D*(double)ns + (double)wsum);
        }
        s_red[tid] = partial;
        __syncthreads();
        for (int s2 = 128; s2 > 0; s2 >>= 1) {
            if (tid < s2) s_red[tid] += s_red[tid + s2];
            __syncthreads();
        }
        if (tid == 0) out[0] = (float)s_red[0];
        return;
    }

    // ===================== BLOCK 1 : precision (round-2-proven path) =========
    if (tid == 0) {
        build_leaf6(eCur, eCur+36, eCur+72, A00, A01, A10, A11, sq6, q, r);
        build_P06(sP0, bias_scales, init_cov);
    }
    __syncthreads();

    // bit-fold: eAcc = TI^T  (T=4096 -> 12 squarings, single bit)
    bool first = true;
    for (int l = 0; l < 14; ++l) {
        if ((T >> l) & 1) {
            if (first) { pcopy(tid, eCur, eAcc, 108); first = false; }
            else {
                pcombine6(tid, eAcc, eCur, eTmp, sW, sM, sT2, sT4, aug, piv);
                pcopy(tid, eTmp, eAcc, 108);
            }
        }
        if ((T >> (l+1)) != 0) {
            pcombine6(tid, eCur, eCur, eTmp, sW, sM, sT2, sT4, aug, piv);
            pcopy(tid, eTmp, eCur, 108);
        }
    }
    // prior fold: P_T6 = accA M P0 accA^T + accC, M = (I + P0 accJ)^-1
    pmul6(tid, sP0, eAcc+72, sW);
    if (tid < 6) sW[tid*6+tid] += 1.f;
    __syncthreads();
    pinv6p(tid, sW, sM, aug, piv);
    pmul6(tid, eAcc, sM, sT2);
    pmul6(tid, sT2, sP0, sW);
    pmulT6(tid, sW, eAcc, sT4);
    if (tid < 36) {
        int i = tid / 6, j = tid % 6;
        sPT6[tid] = 0.5f*(sT4[i*6+j]+sT4[j*6+i]) + 0.5f*(eAcc[36+i*6+j]+eAcc[36+j*6+i]);
    }
    __syncthreads();

    // f64 Gauss-Jordan inverse of P_T6 (round-2 verbatim)
    if (tid == 0) {
        double MI[6][12];
        #pragma unroll
        for (int i = 0; i < 6; ++i)
            #pragma unroll
            for (int j = 0; j < 6; ++j) {
                MI[i][j]   = 0.5 * ((double)sPT6[i*6+j] + (double)sPT6[j*6+i]);
                MI[i][6+j] = (i == j) ? 1.0 : 0.0;
            }
        #pragma unroll
        for (int cc = 0; cc < 6; ++cc) {
            double pv = 1.0 / MI[cc][cc];
            #pragma unroll
            for (int j = 0; j < 12; ++j) MI[cc][j] *= pv;
            #pragma unroll
            for (int rr = 0; rr < 6; ++rr) {
                if (rr == cc) continue;
                double f = MI[rr][cc];
                #pragma unroll
                for (int j = 0; j < 12; ++j) MI[rr][j] -= f * MI[cc][j];
            }
        }
        #pragma unroll
        for (int i = 0; i < 6; ++i)
            #pragma unroll
            for (int j = 0; j < 6; ++j)
                sQd[i*6+j] = 0.5 * (MI[i][6+j] + MI[j][6+i]);
        const double rd  = (double)r;
        const double dd0 = (double)d0p0, dd1 = (double)d0p1;
        sSc[0] = dd0*rd / (rd + (double)T*dd0);
        sSc[1] = dd1*rd / (rd + (double)T*dd1);
    }
    __syncthreads();

    // scatter (round-2 verbatim), out[1..]
    const double dTp0 = sSc[0], dTp1 = sSc[1];
    const double inv_sqn = 1.0 / sqrt(dn);
    const int D  = 2*S + 2;
    const int ob = D - 2;
    for (int idx = 1 + tid; idx < out_size; idx += 256) {
        int e = idx - 1;
        int row = e / D;
        int col = e - row * D;
        double v;
        if (row < ob && col < ob) {
            int tr = ((row / S) << 1) | (row & 1);
            int tc = ((col / S) << 1) | (col & 1);
            v = sQd[tr*6 + tc] / dn;
            if (tr == tc) {
                double dt = (tr & 1) ? dTp1 : dTp0;
                v -= 1.0 / (dn * dt);
                if (row == col) v += 1.0 / dt;
            }
        } else if (row < ob) {
            int tr = ((row / S) << 1) | (row & 1);
            v = sQd[tr*6 + 4 + (col - ob)] * inv_sqn;
        } else if (col < ob) {
            int tc = ((col / S) << 1) | (col & 1);
            v = sQd[(4 + row - ob)*6 + tc] * inv_sqn;
        } else {
            v = sQd[(4 + row - ob)*6 + (4 + col - ob)];
        }
        out[idx] = (float)v;
    }
}

extern "C" void kernel_launch(void* const* d_in, const int* in_sizes, int n_in,
                              void* d_out, int out_size, void* d_ws, size_t ws_size,
                              hipStream_t stream) {
    const float* track        = (const float*)d_in[0];
    const float* bias_scales  = (const float*)d_in[1];
    const float* obs_noise    = (const float*)d_in[2];
    const float* trans_noise  = (const float*)d_in[3];
    const float* Amat         = (const float*)d_in[4];
    const float* init_cov     = (const float*)d_in[5];
    const int*   num_sensors  = (const int*)d_in[6];

    const int T = in_sizes[0] / 2;   // 4096

    k_all<<<2, 256, 0, stream>>>(track, bias_scales, obs_noise, trans_noise,
                                 Amat, init_cov, num_sensors,
                                 (float*)d_out, out_size, T);
}